// Round 1
// 685.855 us; speedup vs baseline: 1.0015x; 1.0015x over previous
//
#include <hip/hip_runtime.h>
#include <math.h>

// Problem constants
#define K_CODES   1024
#define D_DIM     256
#define HW_SZ     1024          // 32*32
#define N_TOT     65536         // 64 * 1024
#define ND_TOT    16777216.0f   // N_TOT * D_DIM

// Output layout (float32, concatenated in reference return order)
#define O_ZQ    0
#define O_LOSS  16777216
#define O_IDX   16777217
#define O_CB    16842753
#define O_CS    17104897
#define O_DW    17105921

// Scratch offsets inside the O_ZQ region (float units). All dead before k_zt
// overwrites the region with zflat.
#define ZHALF_OFF 0           // 65536x256 f16 = 8388608 floats
#define CHALF_OFF 8388608     // 1024x256 f16  = 131072 floats
#define PM2_OFF   8519680     // 4x65536 f32 second-min partials
#define ZN_OFF    8781824     // 65536 f32 row norms
#define L1_OFF    8847360     // 65536 f32 row L1 norms (for THR bound)
#define FLAG_OFF  8912896     // 65536 int flagged-row list

typedef float f2 __attribute__((ext_vector_type(2)));
typedef float f32x4 __attribute__((ext_vector_type(4)));
typedef _Float16 f16;
typedef _Float16 f16x8 __attribute__((ext_vector_type(8)));
typedef _Float16 f16x4 __attribute__((ext_vector_type(4)));

// ---------------------------------------------------------------------------
// Per-code squared norms, numpy-pairwise fp32 semantics (contract OFF).
__global__ void k_cnorm(const float* __restrict__ cb, float* __restrict__ cn) {
#pragma clang fp contract(off)
    int k = blockIdx.x * 256 + threadIdx.x;            // grid = 4 blocks
    const float* row = cb + (size_t)k * D_DIM;
    float s1 = 0.f, s2 = 0.f;
#pragma unroll
    for (int blk = 0; blk < 2; ++blk) {
        const float* p = row + blk * 128;
        float r[8];
#pragma unroll
        for (int j = 0; j < 8; ++j) { float v = p[j]; r[j] = v * v; }
        for (int i = 8; i < 128; i += 8) {
#pragma unroll
            for (int j = 0; j < 8; ++j) { float v = p[i + j]; r[j] = r[j] + v * v; }
        }
        float s = ((r[0] + r[1]) + (r[2] + r[3])) + ((r[4] + r[5]) + (r[6] + r[7]));
        if (blk == 0) s1 = s; else s2 = s;
    }
    cn[k] = s1 + s2;
}

// ---------------------------------------------------------------------------
// Per-row squared norms (bit-identical to the passing version) + L1 norms
// (any order; only feeds the rescue threshold bound).
__global__ void k_zn2(const float* __restrict__ ze, float* __restrict__ zn,
                      float* __restrict__ l1) {
#pragma clang fp contract(off)
    int n = blockIdx.x * 256 + threadIdx.x;            // grid = 256 blocks
    int b = n >> 10, hw = n & 1023;
    const float* p = ze + (size_t)b * (D_DIM * HW_SZ) + hw;
    float s1 = 0.f, s2 = 0.f, a1 = 0.f;
#pragma unroll
    for (int blk = 0; blk < 2; ++blk) {
        const float* q = p + (size_t)(blk * 128) * HW_SZ;
        float r[8], qa[8];
#pragma unroll
        for (int j = 0; j < 8; ++j) {
            float v = q[(size_t)j * HW_SZ];
            r[j] = v * v; qa[j] = fabsf(v);
        }
        for (int i = 8; i < 128; i += 8) {
#pragma unroll
            for (int j = 0; j < 8; ++j) {
                float v = q[(size_t)(i + j) * HW_SZ];
                r[j] = r[j] + v * v;
                qa[j] = qa[j] + fabsf(v);
            }
        }
        float s = ((r[0] + r[1]) + (r[2] + r[3])) + ((r[4] + r[5]) + (r[6] + r[7]));
        a1 += ((qa[0] + qa[1]) + (qa[2] + qa[3])) + ((qa[4] + qa[5]) + (qa[6] + qa[7]));
        if (blk == 0) s1 = s; else s2 = s;
    }
    zn[n] = s1 + s2;
    l1[n] = a1;
}

// ---------------------------------------------------------------------------
// Codebook -> fp16, scaled by 2^10 so values lie in [-1,1] (exact power-of-2
// scale; avoids fp16 denormal flushing in the MFMA).
__global__ __launch_bounds__(256)
void k_prep_c(const float* __restrict__ cb, f16* __restrict__ ch) {
    int i = (blockIdx.x * 256 + threadIdx.x) * 4;      // grid = 256 blocks
    float4 v = *(const float4*)(cb + i);
    f16x4 h;
    h[0] = (f16)(v.x * 1024.0f);
    h[1] = (f16)(v.y * 1024.0f);
    h[2] = (f16)(v.z * 1024.0f);
    h[3] = (f16)(v.w * 1024.0f);
    *(f16x4*)(ch + i) = h;
}

// ---------------------------------------------------------------------------
// z_e [64][256][1024] NCHW -> zhalf [65536][256] row-major fp16.
__global__ __launch_bounds__(256)
void k_prep_z(const float* __restrict__ ze, f16* __restrict__ zh) {
    __shared__ float tile[64][65];
    const int t = threadIdx.x;
    const int hw0 = blockIdx.x * 64;
    const int d0  = blockIdx.y * 64;
    const int b   = blockIdx.z;
    const size_t base_in = (size_t)b * (D_DIM * HW_SZ);
#pragma unroll
    for (int p = 0; p < 4; ++p) {
        int dd = p * 16 + (t >> 4);
        int c4 = (t & 15) * 4;
        float4 v = *(const float4*)(ze + base_in + (size_t)(d0 + dd) * HW_SZ + hw0 + c4);
        tile[dd][c4 + 0] = v.x;
        tile[dd][c4 + 1] = v.y;
        tile[dd][c4 + 2] = v.z;
        tile[dd][c4 + 3] = v.w;
    }
    __syncthreads();
#pragma unroll
    for (int p = 0; p < 4; ++p) {
        int hh  = p * 16 + (t >> 4);
        int dc4 = (t & 15) * 4;
        f16x4 h;
        h[0] = (f16)tile[dc4 + 0][hh];
        h[1] = (f16)tile[dc4 + 1][hh];
        h[2] = (f16)tile[dc4 + 2][hh];
        h[3] = (f16)tile[dc4 + 3][hh];
        *(f16x4*)(zh + (size_t)(b * HW_SZ + hw0 + hh) * D_DIM + d0 + dc4) = h;
    }
}

// ---------------------------------------------------------------------------
// MFMA argmin: grid = (512 n-tiles of 128, 4 k-chunks of 256).
// Tile 128n x 256k, BK=64, 4 waves each owning 128n x 64k (acc 8x4 16x16 frags).
// LDS tiles XOR-swizzled (granule ^= row&7) via pre-swizzled global source +
// linear global_load_lds dest; fragment ds_read_b128 applies the same XOR ->
// 2-way (free) bank aliasing instead of 16-way conflicts.
// Emits per-row (min1, argmin, min2) partials; min2 drives the rescue flag.
__global__ __launch_bounds__(256, 2)
void k_margmin(const f16* __restrict__ zh, const f16* __restrict__ ch,
               const float* __restrict__ cn, const float* __restrict__ zn,
               float* __restrict__ pv, int* __restrict__ pi,
               float* __restrict__ pm2) {
    __shared__ __align__(16) f16 Al[128 * 64];   // 16 KB
    __shared__ __align__(16) f16 Bl[256 * 64];   // 32 KB
    const int t  = threadIdx.x;
    const int w  = t >> 6;       // wave (0..3)
    const int l  = t & 63;       // lane
    const int kc = blockIdx.y;   // k-chunk
    const int n0 = blockIdx.x * 128;
    const int rl = l >> 3;       // staging: row-within-8
    const int gg = l & 7;        // staging: granule
    const int gq = l >> 4;       // frag: quarter-wave group
    const int rr = l & 15;       // frag: row/col within frag

    f32x4 acc[8][4];
#pragma unroll
    for (int a = 0; a < 8; ++a)
#pragma unroll
        for (int b = 0; b < 4; ++b) acc[a][b] = (f32x4)0.f;

    for (int d0 = 0; d0 < 256; d0 += 64) {
        __syncthreads();   // previous iteration's frag reads done
        // stage A (z): 128 rows x 64 d, source granule pre-swizzled
#pragma unroll
        for (int i = 0; i < 4; ++i) {
            int row = w * 32 + i * 8 + rl;
            const f16* g = zh + (size_t)(n0 + row) * D_DIM + d0 + 8 * (gg ^ (row & 7));
            __builtin_amdgcn_global_load_lds(
                (const __attribute__((address_space(1))) void*)g,
                (__attribute__((address_space(3))) void*)((char*)Al + (w * 32 + i * 8) * 128),
                16, 0, 0);
        }
        // stage B (codebook): 256 rows x 64 d
#pragma unroll
        for (int i = 0; i < 8; ++i) {
            int row = w * 64 + i * 8 + rl;
            const f16* g = ch + (size_t)(kc * 256 + row) * D_DIM + d0 + 8 * (gg ^ (row & 7));
            __builtin_amdgcn_global_load_lds(
                (const __attribute__((address_space(1))) void*)g,
                (__attribute__((address_space(3))) void*)((char*)Bl + (w * 64 + i * 8) * 128),
                16, 0, 0);
        }
        __syncthreads();
#pragma unroll
        for (int ks = 0; ks < 2; ++ks) {
            f16x8 af[8], bf[4];
#pragma unroll
            for (int nf = 0; nf < 8; ++nf) {
                int row = nf * 16 + rr;
                af[nf] = *(const f16x8*)((char*)Al + row * 128 +
                                         16 * ((ks * 4 + gq) ^ (row & 7)));
            }
#pragma unroll
            for (int kf = 0; kf < 4; ++kf) {
                int row = w * 64 + kf * 16 + rr;
                bf[kf] = *(const f16x8*)((char*)Bl + row * 128 +
                                         16 * ((ks * 4 + gq) ^ (row & 7)));
            }
#pragma unroll
            for (int nf = 0; nf < 8; ++nf)
#pragma unroll
                for (int kf = 0; kf < 4; ++kf)
                    acc[nf][kf] = __builtin_amdgcn_mfma_f32_16x16x32_f16(
                        af[nf], bf[kf], acc[nf][kf], 0, 0, 0);
        }
    }
    __syncthreads();   // all frag reads done before Al reuse

    // Fold + per-row (min1, idx1, min2). D layout: row n = (l>>4)*4 + reg,
    // col k = l&15 (m89-verified C/D mapping).
    float* red = (float*)Al;   // 4 waves x 128 rows x 3 floats = 6 KB
    float cnv[4];
#pragma unroll
    for (int kf = 0; kf < 4; ++kf)
        cnv[kf] = cn[kc * 256 + w * 64 + kf * 16 + rr];
#pragma unroll
    for (int nf = 0; nf < 8; ++nf) {
#pragma unroll
        for (int r = 0; r < 4; ++r) {
            float znv = zn[n0 + nf * 16 + gq * 4 + r];
            float m1 = INFINITY, m2 = INFINITY; int i1 = 0;
#pragma unroll
            for (int kf = 0; kf < 4; ++kf) {
                float g  = acc[nf][kf][r] * 0x1p-10f;  // undo codebook scale (exact)
                float tt = znv - 2.0f * g;
                float s  = tt + cnv[kf];
                int k = kc * 256 + w * 64 + kf * 16 + rr;
                if (s < m1) { m2 = m1; m1 = s; i1 = k; }
                else        { m2 = fminf(m2, s); }
            }
            // reduce across the 16 lanes holding this row's 64 k values
            for (int off = 1; off < 16; off <<= 1) {
                float o1 = __shfl_xor(m1, off, 64);
                float o2 = __shfl_xor(m2, off, 64);
                int   oi = __shfl_xor(i1, off, 64);
                if (o1 < m1) { m2 = fminf(m1, o2); m1 = o1; i1 = oi; }
                else         { m2 = fminf(m2, o1); }
            }
            if (rr == 0) {
                int nl = nf * 16 + gq * 4 + r;
                red[(w * 128 + nl) * 3 + 0] = m1;
                red[(w * 128 + nl) * 3 + 1] = __int_as_float(i1);
                red[(w * 128 + nl) * 3 + 2] = m2;
            }
        }
    }
    __syncthreads();
    if (t < 128) {
        float m1 = INFINITY, m2 = INFINITY; int i1 = 0;
#pragma unroll
        for (int w2 = 0; w2 < 4; ++w2) {
            float a1 = red[(w2 * 128 + t) * 3 + 0];
            int   ai = __float_as_int(red[(w2 * 128 + t) * 3 + 1]);
            float a2 = red[(w2 * 128 + t) * 3 + 2];
            if (a1 < m1) { m2 = fminf(m1, a2); m1 = a1; i1 = ai; }
            else         { m2 = fminf(m2, a1); }
        }
        pv [kc * N_TOT + n0 + t] = m1;
        pi [kc * N_TOT + n0 + t] = i1;
        pm2[kc * N_TOT + n0 + t] = m2;
    }
}

// ---------------------------------------------------------------------------
// Combine 4 k-chunk partials, emit approx indices + counts, and flag rows
// whose second-best score is within THR of the min (THR = sound bound on
// |s_fp16 - s_exact|: 2*2^-20*L1 conversion term (1.5x margin) + fold/accum
// constant). Unflagged rows are PROVABLY the exact argmin.
__global__ __launch_bounds__(256)
void k_combine2(const float* __restrict__ pv, const int* __restrict__ pi,
                const float* __restrict__ pm2, const float* __restrict__ l1b,
                float* __restrict__ out_idx, float* __restrict__ counts,
                int* __restrict__ flaglist, int* __restrict__ flagn) {
    int n = blockIdx.x * 256 + threadIdx.x;
    float m1 = INFINITY, m2 = INFINITY; int i1 = 0;
#pragma unroll
    for (int c = 0; c < 4; ++c) {
        float a1 = pv [c * N_TOT + n];
        int   ai = pi [c * N_TOT + n];
        float a2 = pm2[c * N_TOT + n];
        if (a1 < m1) { m2 = fminf(m1, a2); m1 = a1; i1 = ai; }
        else         { m2 = fminf(m2, a1); }
    }
    out_idx[n] = (float)i1;
    atomicAdd(counts + i1, 1.0f);
    float thr = l1b[n] * 2.9e-6f + 2.5e-4f;
    if (m2 <= m1 + thr) {
        int p = atomicAdd(flagn, 1);
        flaglist[p] = n;
    }
}

// ---------------------------------------------------------------------------
// Exact rescore of flagged rows over ALL 1024 codes, reproducing the original
// passing kernel's arithmetic bit-exactly: G = sequential fmaf over ascending
// d; s = fl(fl(zn - 2G) + cn); strict-< ascending-k => first-index ties.
// 16 rows per block; codebook staged in two 512-code halves (LDS < 64 KB).
// Reads z_e directly (L3-hot) so it can run before k_zt.
__global__ __launch_bounds__(256)
void k_rescue(const float* __restrict__ ze, const float* __restrict__ cb,
              const float* __restrict__ cn, const float* __restrict__ znb,
              const int* __restrict__ flaglist, const int* __restrict__ flagn,
              float* __restrict__ out_idx, float* __restrict__ counts) {
    __shared__ float zl[16][256];    // 16 KB
    __shared__ float cl[512][20];    // 40 KB (pad 20: 16B-aligned, bank-spread)
    __shared__ float cnl[1024];      // 4 KB
    __shared__ int rows[16];
    const int t   = threadIdx.x;
    const int nf  = *flagn;
    const int row = t >> 4;
    const int kl  = t & 15;
#pragma unroll
    for (int i = 0; i < 4; ++i) cnl[i * 256 + t] = cn[i * 256 + t];

    for (int grp = blockIdx.x; grp * 16 < nf; grp += gridDim.x) {
        __syncthreads();                  // protect rows/zl/cl reuse
        if (t < 16) {
            int ii = grp * 16 + t;
            rows[t] = flaglist[ii < nf ? ii : grp * 16];
        }
        __syncthreads();
        // stage z rows: thread t loads d=t for all 16 rows (strided; L3-hot)
#pragma unroll 4
        for (int j = 0; j < 16; ++j) {
            int n = rows[j];
            int b = n >> 10, hw = n & 1023;
            zl[j][t] = ze[(size_t)b * (D_DIM * HW_SZ) + (size_t)t * HW_SZ + hw];
        }
        float bs = INFINITY; int bk = 0;
        for (int kp = 0; kp < 2; ++kp) {
            float acc[32];
#pragma unroll
            for (int j2 = 0; j2 < 32; ++j2) acc[j2] = 0.f;
            for (int dt = 0; dt < 16; ++dt) {
                __syncthreads();
#pragma unroll
                for (int j = 0; j < 8; ++j) {       // stage 512 x 16 fp32 tile
                    int idx = j * 256 + t;
                    int kk = idx >> 2, dd4 = (idx & 3) * 4;
                    float4 v = *(const float4*)(cb + (size_t)(kp * 512 + kk) * D_DIM
                                                + dt * 16 + dd4);
                    *(float4*)&cl[kk][dd4] = v;
                }
                __syncthreads();
                float zr[16];
#pragma unroll
                for (int dd = 0; dd < 16; ++dd) zr[dd] = zl[row][dt * 16 + dd];
#pragma unroll 4
                for (int j2 = 0; j2 < 32; ++j2) {
                    const float* cr = &cl[j2 * 16 + kl][0];
                    float a = acc[j2];
#pragma unroll
                    for (int dd = 0; dd < 16; ++dd) a = fmaf(zr[dd], cr[dd], a);
                    acc[j2] = a;
                }
            }
            float znj = znb[rows[row]];
#pragma unroll
            for (int j2 = 0; j2 < 32; ++j2) {
                int k = kp * 512 + j2 * 16 + kl;
                float tt = znj - 2.0f * acc[j2];
                float s  = tt + cnl[k];
                if (s < bs || (s == bs && k < bk)) { bs = s; bk = k; }
            }
        }
        // lexicographic (value, index) min across the 16 lanes of this row
        for (int off = 1; off < 16; off <<= 1) {
            float os = __shfl_xor(bs, off, 64);
            int   ok = __shfl_xor(bk, off, 64);
            if (os < bs || (os == bs && ok < bk)) { bs = os; bk = ok; }
        }
        if (kl == 0 && grp * 16 + row < nf) {
            int n = rows[row];
            int old = (int)out_idx[n];
            if (old != bk) {
                out_idx[n] = (float)bk;
                atomicAdd(counts + old, -1.0f);
                atomicAdd(counts + bk,  1.0f);
            }
        }
    }
}

// ---------------------------------------------------------------------------
// Transpose z_e [64][256][1024] -> zflat [65536][256] (into O_ZQ region,
// overwriting the now-dead fp16/partial scratch).
__global__ __launch_bounds__(256)
void k_zt(const float* __restrict__ ze, float* __restrict__ zflat) {
    __shared__ float tile[64][65];
    const int t = threadIdx.x;
    const int hw0 = blockIdx.x * 64;
    const int d0  = blockIdx.y * 64;
    const int b   = blockIdx.z;
    const size_t base_in = (size_t)b * (D_DIM * HW_SZ);
#pragma unroll
    for (int p = 0; p < 4; ++p) {
        int dd = p * 16 + (t >> 4);
        int c4 = (t & 15) * 4;
        float4 v = *(const float4*)(ze + base_in + (size_t)(d0 + dd) * HW_SZ + hw0 + c4);
        tile[dd][c4 + 0] = v.x;
        tile[dd][c4 + 1] = v.y;
        tile[dd][c4 + 2] = v.z;
        tile[dd][c4 + 3] = v.w;
    }
    __syncthreads();
#pragma unroll
    for (int p = 0; p < 4; ++p) {
        int hh  = p * 16 + (t >> 4);
        int dc4 = (t & 15) * 4;
        float4 v = { tile[dc4 + 0][hh], tile[dc4 + 1][hh],
                     tile[dc4 + 2][hh], tile[dc4 + 3][hh] };
        *(float4*)(zflat + (size_t)(b * HW_SZ + hw0 + hh) * D_DIM + d0 + dc4) = v;
    }
}

// ---------------------------------------------------------------------------
// EMA cluster size + smoothed (loss finalize lives in k_zq).
__global__ __launch_bounds__(1024)
void k_ema_cs(const float* __restrict__ ema_cs, const float* __restrict__ counts,
              float* __restrict__ out_cs, float* __restrict__ smoothed) {
    __shared__ float red[1024];
    int k = threadIdx.x;
    float cs_new = fmaf(0.99f, ema_cs[k], 0.01f * counts[k]);
    red[k] = cs_new;
    __syncthreads();
    for (int off = 512; off > 0; off >>= 1) {
        if (k < off) red[k] += red[k + off];
        __syncthreads();
    }
    float ntot = red[0];
    out_cs[k] = cs_new;
    smoothed[k] = (cs_new + 1e-5f) / (ntot + 0.01024f) * ntot;
}

// ---------------------------------------------------------------------------
// Per-code segment sum: one block per code; compact matching rows into an LDS
// queue, sum rows coalesced from zflat with 2-way load ILP. Fuses loss
// partials + dw EMA + cb write.
__global__ __launch_bounds__(256)
void k_dwsum(const float* __restrict__ idxf, const float* __restrict__ zflat,
             const float* __restrict__ cb, const float* __restrict__ ema_dw,
             const float* __restrict__ smoothed, float* __restrict__ out_dw,
             float* __restrict__ out_cb, float* __restrict__ lossacc) {
    __shared__ int queue[4096];
    __shared__ int qn;
    __shared__ float lred[4];

    const int k = blockIdx.x;
    const int t = threadIdx.x;
    const float fk = (float)k;
    const float ck = cb[(size_t)k * D_DIM + t];

    float acc = 0.f;
    float ls  = 0.f;

    for (int chunk = 0; chunk < 16; ++chunk) {
        if (t == 0) qn = 0;
        __syncthreads();
#pragma unroll
        for (int j = 0; j < 16; ++j) {
            int n = chunk * 4096 + j * 256 + t;        // coalesced idx read
            if (idxf[n] == fk) {
                int p = atomicAdd(&qn, 1);
                queue[p] = n;
            }
        }
        __syncthreads();
        int m = qn;
        int i = 0;
        for (; i + 1 < m; i += 2) {                    // 2-way load ILP
            int n1 = queue[i], n2 = queue[i + 1];
            float z1 = zflat[(size_t)n1 * D_DIM + t];
            float z2 = zflat[(size_t)n2 * D_DIM + t];
            acc += z1; float d1 = ck - z1; ls += d1 * d1;
            acc += z2; float d2 = ck - z2; ls += d2 * d2;
        }
        if (i < m) {
            int n1 = queue[i];
            float z1 = zflat[(size_t)n1 * D_DIM + t];
            acc += z1; float d1 = ck - z1; ls += d1 * d1;
        }
        __syncthreads();   // all queue reads done before next chunk's writes
    }

    size_t o = (size_t)k * D_DIM + t;
    float nd = fmaf(0.99f, ema_dw[o], 0.01f * acc);
    out_dw[o] = nd;
    out_cb[o] = nd / smoothed[k];

#pragma unroll
    for (int off = 32; off > 0; off >>= 1) ls += __shfl_down(ls, off, 64);
    if ((t & 63) == 0) lred[t >> 6] = ls;
    __syncthreads();
    if (t == 0) atomicAdd(lossacc, lred[0] + lred[1] + lred[2] + lred[3]);
}

// ---------------------------------------------------------------------------
// Straight-through z_q writer: pure float4 stream + L2 codebook gather.
// Also finalizes the loss (lossacc complete from k_dwsum, stream-ordered).
__global__ __launch_bounds__(256)
void k_zq(const float* __restrict__ ze, const float* __restrict__ cb,
          const float* __restrict__ idxf, float* __restrict__ out0,
          const float* __restrict__ lossacc, float* __restrict__ out_loss) {
    const int t = threadIdx.x;
    int g   = blockIdx.x * 64 + (t & 63);   // hw4-group id in [0, 16384)
    int b   = g >> 8;
    int hwl = (g & 255) * 4;
    int dg  = t >> 6;                        // d-quarter (0..3)
    const size_t base = (size_t)b * (D_DIM * HW_SZ) + hwl;

    int i0 = (int)idxf[b * HW_SZ + hwl + 0];
    int i1 = (int)idxf[b * HW_SZ + hwl + 1];
    int i2 = (int)idxf[b * HW_SZ + hwl + 2];
    int i3 = (int)idxf[b * HW_SZ + hwl + 3];
    const float* c0 = cb + (size_t)i0 * D_DIM;
    const float* c1 = cb + (size_t)i1 * D_DIM;
    const float* c2 = cb + (size_t)i2 * D_DIM;
    const float* c3 = cb + (size_t)i3 * D_DIM;

#pragma unroll 2
    for (int i = 0; i < 64; ++i) {
        int d = dg * 64 + i;
        size_t o = base + (size_t)d * HW_SZ;
        float4 z = *(const float4*)(ze + o);
        float4 r;
        r.x = z.x + (c0[d] - z.x);
        r.y = z.y + (c1[d] - z.y);
        r.z = z.z + (c2[d] - z.z);
        r.w = z.w + (c3[d] - z.w);
        *(float4*)(out0 + o) = r;
    }

    if (blockIdx.x == 0 && t == 0)
        out_loss[0] = 0.5f * lossacc[0] / ND_TOT;
}

// ---------------------------------------------------------------------------
extern "C" void kernel_launch(void* const* d_in, const int* in_sizes, int n_in,
                              void* d_out, int out_size, void* d_ws, size_t ws_size,
                              hipStream_t stream) {
    const float* ze     = (const float*)d_in[0];  // [64,256,32,32]
    const float* cb     = (const float*)d_in[1];  // [1024,256]
    const float* emacs  = (const float*)d_in[2];  // [1024]
    const float* emadw  = (const float*)d_in[3];  // [1024,256]
    float* out = (float*)d_out;
    float* ws  = (float*)d_ws;

    // Scratch choreography (stream-ordered reuse of d_out's O_ZQ region):
    //   ZH (fp16 zflat)  : k_prep_z -> k_margmin -> dead
    //   CH (fp16 cb*2^10): k_prep_c -> k_margmin -> dead
    //   PM2              : k_margmin -> k_combine2 -> dead
    //   ZN/L1            : k_zn2 -> k_margmin/k_combine2/k_rescue -> dead
    //   FLAG             : k_combine2 -> k_rescue -> dead
    //   zflat (fp32)     : k_zt (AFTER rescue) -> k_dwsum -> overwritten by k_zq
    //   PV/PI            : k_margmin -> k_combine2 -> overwritten by
    //                      k_dwsum (out_cb) / k_ema_cs+k_dwsum (out_cs/out_dw)
    f16*   ZH    = (f16*)(out + ZHALF_OFF);
    f16*   CH    = (f16*)(out + CHALF_OFF);
    float* PM2   = out + PM2_OFF;
    float* ZNb   = out + ZN_OFF;
    float* L1b   = out + L1_OFF;
    int*   FLAG  = (int*)(out + FLAG_OFF);
    float* ZFLAT = out;
    float* PV    = out + O_CB;
    int*   PI    = (int*)(out + O_CS);
    // d_ws scratch (same ~13 KB footprint as before)
    float* counts   = ws;                 // 1024
    float* lossacc  = ws + 1024;          // 1
    int*   flagn    = (int*)(ws + 1025);  // 1
    float* smoothed = ws + 1088;          // 1024
    float* CN       = ws + 2112;          // 1024

    hipMemsetAsync(ws, 0, 1032 * sizeof(float), stream);

    k_cnorm<<<4, 256, 0, stream>>>(cb, CN);
    k_zn2<<<256, 256, 0, stream>>>(ze, ZNb, L1b);
    k_prep_c<<<256, 256, 0, stream>>>(cb, CH);
    k_prep_z<<<dim3(16, 4, 64), 256, 0, stream>>>(ze, ZH);
    k_margmin<<<dim3(512, 4), 256, 0, stream>>>(ZH, CH, CN, ZNb, PV, PI, PM2);
    k_combine2<<<256, 256, 0, stream>>>(PV, PI, PM2, L1b, out + O_IDX, counts,
                                        FLAG, flagn);
    k_rescue<<<512, 256, 0, stream>>>(ze, cb, CN, ZNb, FLAG, flagn,
                                      out + O_IDX, counts);
    k_zt<<<dim3(16, 4, 64), 256, 0, stream>>>(ze, ZFLAT);
    k_ema_cs<<<1, 1024, 0, stream>>>(emacs, counts, out + O_CS, smoothed);
    k_dwsum<<<K_CODES, 256, 0, stream>>>(out + O_IDX, ZFLAT, cb, emadw, smoothed,
                                         out + O_DW, out + O_CB, lossacc);
    k_zq<<<256, 256, 0, stream>>>(ze, cb, out + O_IDX, out + O_ZQ,
                                  lossacc, out + O_LOSS);
}

// Round 2
// 565.378 us; speedup vs baseline: 1.2149x; 1.2131x over previous
//
#include <hip/hip_runtime.h>
#include <math.h>

// Problem constants
#define K_CODES   1024
#define D_DIM     256
#define HW_SZ     1024          // 32*32
#define N_TOT     65536         // 64 * 1024
#define ND_TOT    16777216.0f   // N_TOT * D_DIM

// Output layout (float32, concatenated in reference return order)
#define O_ZQ    0
#define O_LOSS  16777216
#define O_IDX   16777217
#define O_CB    16842753
#define O_CS    17104897
#define O_DW    17105921

// Scratch inside the O_ZQ region (float units). ALL dead before k_zt
// overwrites the region with zflat (k_zt runs after k_combine2 now).
#define ZHALF_OFF 0           // 65536x256 f16 = 8388608 floats
#define CHALF_OFF 8388608     // 1024x256 f16  = 131072 floats
#define PM2_OFF   8519680     // 4x65536 f32 second-min partials
#define PV_OFF    8781824     // 4x65536 f32 min partials
#define PI_OFF    9043968     // 4x65536 int argmin partials
#define L1_OFF    9306112     // 65536 f32 row L1 norms (for THR bound)
// Scratch in the output tail (survives k_zt; dead before k_dwsum/k_ema_cs):
//   CT  [256][1024] f32 at out+O_CB  (1 MB; overwritten by out_cb)
//   ZN  65536 f32       at out+O_DW  (overwritten by out_dw)
//   FLG 65536 int       at out+O_DW+65536

typedef float f2 __attribute__((ext_vector_type(2)));
typedef float f32x4 __attribute__((ext_vector_type(4)));
typedef _Float16 f16;
typedef _Float16 f16x8 __attribute__((ext_vector_type(8)));
typedef _Float16 f16x4 __attribute__((ext_vector_type(4)));

// ---------------------------------------------------------------------------
// Transpose codebook [K][D] -> CT [D][K] (for the rescue's register GEMM).
__global__ void k_transpose(const float* __restrict__ cb, float* __restrict__ ct) {
    __shared__ float tile[32][33];
    int k0 = blockIdx.x * 32;
    int d0 = blockIdx.y * 32;
    int c = threadIdx.x & 31, r0 = threadIdx.x >> 5;
#pragma unroll
    for (int p = 0; p < 4; ++p) {
        int r = r0 + p * 8;
        tile[r][c] = cb[(k0 + r) * D_DIM + d0 + c];
    }
    __syncthreads();
#pragma unroll
    for (int p = 0; p < 4; ++p) {
        int r = r0 + p * 8;
        ct[(size_t)(d0 + r) * K_CODES + k0 + c] = tile[c][r];
    }
}

// ---------------------------------------------------------------------------
// Per-code squared norms, numpy-pairwise fp32 semantics (contract OFF).
__global__ void k_cnorm(const float* __restrict__ cb, float* __restrict__ cn) {
#pragma clang fp contract(off)
    int k = blockIdx.x * 256 + threadIdx.x;            // grid = 4 blocks
    const float* row = cb + (size_t)k * D_DIM;
    float s1 = 0.f, s2 = 0.f;
#pragma unroll
    for (int blk = 0; blk < 2; ++blk) {
        const float* p = row + blk * 128;
        float r[8];
#pragma unroll
        for (int j = 0; j < 8; ++j) { float v = p[j]; r[j] = v * v; }
        for (int i = 8; i < 128; i += 8) {
#pragma unroll
            for (int j = 0; j < 8; ++j) { float v = p[i + j]; r[j] = r[j] + v * v; }
        }
        float s = ((r[0] + r[1]) + (r[2] + r[3])) + ((r[4] + r[5]) + (r[6] + r[7]));
        if (blk == 0) s1 = s; else s2 = s;
    }
    cn[k] = s1 + s2;
}

// ---------------------------------------------------------------------------
// Per-row squared norms (bit-identical fold) + L1 norms (feeds THR bound).
__global__ void k_zn2(const float* __restrict__ ze, float* __restrict__ zn,
                      float* __restrict__ l1) {
#pragma clang fp contract(off)
    int n = blockIdx.x * 256 + threadIdx.x;            // grid = 256 blocks
    int b = n >> 10, hw = n & 1023;
    const float* p = ze + (size_t)b * (D_DIM * HW_SZ) + hw;
    float s1 = 0.f, s2 = 0.f, a1 = 0.f;
#pragma unroll
    for (int blk = 0; blk < 2; ++blk) {
        const float* q = p + (size_t)(blk * 128) * HW_SZ;
        float r[8], qa[8];
#pragma unroll
        for (int j = 0; j < 8; ++j) {
            float v = q[(size_t)j * HW_SZ];
            r[j] = v * v; qa[j] = fabsf(v);
        }
        for (int i = 8; i < 128; i += 8) {
#pragma unroll
            for (int j = 0; j < 8; ++j) {
                float v = q[(size_t)(i + j) * HW_SZ];
                r[j] = r[j] + v * v;
                qa[j] = qa[j] + fabsf(v);
            }
        }
        float s = ((r[0] + r[1]) + (r[2] + r[3])) + ((r[4] + r[5]) + (r[6] + r[7]));
        a1 += ((qa[0] + qa[1]) + (qa[2] + qa[3])) + ((qa[4] + qa[5]) + (qa[6] + qa[7]));
        if (blk == 0) s1 = s; else s2 = s;
    }
    zn[n] = s1 + s2;
    l1[n] = a1;
}

// ---------------------------------------------------------------------------
// Codebook -> fp16, scaled by 2^10 (exact pow2; keeps values in [-1,1]).
__global__ __launch_bounds__(256)
void k_prep_c(const float* __restrict__ cb, f16* __restrict__ ch) {
    int i = (blockIdx.x * 256 + threadIdx.x) * 4;      // grid = 256 blocks
    float4 v = *(const float4*)(cb + i);
    f16x4 h;
    h[0] = (f16)(v.x * 1024.0f);
    h[1] = (f16)(v.y * 1024.0f);
    h[2] = (f16)(v.z * 1024.0f);
    h[3] = (f16)(v.w * 1024.0f);
    *(f16x4*)(ch + i) = h;
}

// ---------------------------------------------------------------------------
// z_e [64][256][1024] NCHW -> zhalf [65536][256] row-major fp16.
__global__ __launch_bounds__(256)
void k_prep_z(const float* __restrict__ ze, f16* __restrict__ zh) {
    __shared__ float tile[64][65];
    const int t = threadIdx.x;
    const int hw0 = blockIdx.x * 64;
    const int d0  = blockIdx.y * 64;
    const int b   = blockIdx.z;
    const size_t base_in = (size_t)b * (D_DIM * HW_SZ);
#pragma unroll
    for (int p = 0; p < 4; ++p) {
        int dd = p * 16 + (t >> 4);
        int c4 = (t & 15) * 4;
        float4 v = *(const float4*)(ze + base_in + (size_t)(d0 + dd) * HW_SZ + hw0 + c4);
        tile[dd][c4 + 0] = v.x;
        tile[dd][c4 + 1] = v.y;
        tile[dd][c4 + 2] = v.z;
        tile[dd][c4 + 3] = v.w;
    }
    __syncthreads();
#pragma unroll
    for (int p = 0; p < 4; ++p) {
        int hh  = p * 16 + (t >> 4);
        int dc4 = (t & 15) * 4;
        f16x4 h;
        h[0] = (f16)tile[dc4 + 0][hh];
        h[1] = (f16)tile[dc4 + 1][hh];
        h[2] = (f16)tile[dc4 + 2][hh];
        h[3] = (f16)tile[dc4 + 3][hh];
        *(f16x4*)(zh + (size_t)(b * HW_SZ + hw0 + hh) * D_DIM + d0 + dc4) = h;
    }
}

// ---------------------------------------------------------------------------
// MFMA argmin (unchanged from round 1): grid = (512 n-tiles, 4 k-chunks).
// Emits per-row (min1, argmin, min2) partials; min2 drives the rescue flag.
__global__ __launch_bounds__(256, 2)
void k_margmin(const f16* __restrict__ zh, const f16* __restrict__ ch,
               const float* __restrict__ cn, const float* __restrict__ zn,
               float* __restrict__ pv, int* __restrict__ pi,
               float* __restrict__ pm2) {
    __shared__ __align__(16) f16 Al[128 * 64];   // 16 KB
    __shared__ __align__(16) f16 Bl[256 * 64];   // 32 KB
    const int t  = threadIdx.x;
    const int w  = t >> 6;       // wave (0..3)
    const int l  = t & 63;       // lane
    const int kc = blockIdx.y;   // k-chunk
    const int n0 = blockIdx.x * 128;
    const int rl = l >> 3;       // staging: row-within-8
    const int gg = l & 7;        // staging: granule
    const int gq = l >> 4;       // frag: quarter-wave group
    const int rr = l & 15;       // frag: row/col within frag

    f32x4 acc[8][4];
#pragma unroll
    for (int a = 0; a < 8; ++a)
#pragma unroll
        for (int b = 0; b < 4; ++b) acc[a][b] = (f32x4)0.f;

    for (int d0 = 0; d0 < 256; d0 += 64) {
        __syncthreads();   // previous iteration's frag reads done
        // stage A (z): 128 rows x 64 d, source granule pre-swizzled
#pragma unroll
        for (int i = 0; i < 4; ++i) {
            int row = w * 32 + i * 8 + rl;
            const f16* g = zh + (size_t)(n0 + row) * D_DIM + d0 + 8 * (gg ^ (row & 7));
            __builtin_amdgcn_global_load_lds(
                (const __attribute__((address_space(1))) void*)g,
                (__attribute__((address_space(3))) void*)((char*)Al + (w * 32 + i * 8) * 128),
                16, 0, 0);
        }
        // stage B (codebook): 256 rows x 64 d
#pragma unroll
        for (int i = 0; i < 8; ++i) {
            int row = w * 64 + i * 8 + rl;
            const f16* g = ch + (size_t)(kc * 256 + row) * D_DIM + d0 + 8 * (gg ^ (row & 7));
            __builtin_amdgcn_global_load_lds(
                (const __attribute__((address_space(1))) void*)g,
                (__attribute__((address_space(3))) void*)((char*)Bl + (w * 64 + i * 8) * 128),
                16, 0, 0);
        }
        __syncthreads();
#pragma unroll
        for (int ks = 0; ks < 2; ++ks) {
            f16x8 af[8], bf[4];
#pragma unroll
            for (int nf = 0; nf < 8; ++nf) {
                int row = nf * 16 + rr;
                af[nf] = *(const f16x8*)((char*)Al + row * 128 +
                                         16 * ((ks * 4 + gq) ^ (row & 7)));
            }
#pragma unroll
            for (int kf = 0; kf < 4; ++kf) {
                int row = w * 64 + kf * 16 + rr;
                bf[kf] = *(const f16x8*)((char*)Bl + row * 128 +
                                         16 * ((ks * 4 + gq) ^ (row & 7)));
            }
#pragma unroll
            for (int nf = 0; nf < 8; ++nf)
#pragma unroll
                for (int kf = 0; kf < 4; ++kf)
                    acc[nf][kf] = __builtin_amdgcn_mfma_f32_16x16x32_f16(
                        af[nf], bf[kf], acc[nf][kf], 0, 0, 0);
        }
    }
    __syncthreads();   // all frag reads done before Al reuse

    // Fold + per-row (min1, idx1, min2). D layout: row n = (l>>4)*4 + reg,
    // col k = l&15 (m89-verified C/D mapping).
    float* red = (float*)Al;   // 4 waves x 128 rows x 3 floats = 6 KB
    float cnv[4];
#pragma unroll
    for (int kf = 0; kf < 4; ++kf)
        cnv[kf] = cn[kc * 256 + w * 64 + kf * 16 + rr];
#pragma unroll
    for (int nf = 0; nf < 8; ++nf) {
#pragma unroll
        for (int r = 0; r < 4; ++r) {
            float znv = zn[n0 + nf * 16 + gq * 4 + r];
            float m1 = INFINITY, m2 = INFINITY; int i1 = 0;
#pragma unroll
            for (int kf = 0; kf < 4; ++kf) {
                float g  = acc[nf][kf][r] * 0x1p-10f;  // undo codebook scale (exact)
                float tt = znv - 2.0f * g;
                float s  = tt + cnv[kf];
                int k = kc * 256 + w * 64 + kf * 16 + rr;
                if (s < m1) { m2 = m1; m1 = s; i1 = k; }
                else        { m2 = fminf(m2, s); }
            }
            // reduce across the 16 lanes holding this row's 64 k values
            for (int off = 1; off < 16; off <<= 1) {
                float o1 = __shfl_xor(m1, off, 64);
                float o2 = __shfl_xor(m2, off, 64);
                int   oi = __shfl_xor(i1, off, 64);
                if (o1 < m1) { m2 = fminf(m1, o2); m1 = o1; i1 = oi; }
                else         { m2 = fminf(m2, o1); }
            }
            if (rr == 0) {
                int nl = nf * 16 + gq * 4 + r;
                red[(w * 128 + nl) * 3 + 0] = m1;
                red[(w * 128 + nl) * 3 + 1] = __int_as_float(i1);
                red[(w * 128 + nl) * 3 + 2] = m2;
            }
        }
    }
    __syncthreads();
    if (t < 128) {
        float m1 = INFINITY, m2 = INFINITY; int i1 = 0;
#pragma unroll
        for (int w2 = 0; w2 < 4; ++w2) {
            float a1 = red[(w2 * 128 + t) * 3 + 0];
            int   ai = __float_as_int(red[(w2 * 128 + t) * 3 + 1]);
            float a2 = red[(w2 * 128 + t) * 3 + 2];
            if (a1 < m1) { m2 = fminf(m1, a2); m1 = a1; i1 = ai; }
            else         { m2 = fminf(m2, a1); }
        }
        pv [kc * N_TOT + n0 + t] = m1;
        pi [kc * N_TOT + n0 + t] = i1;
        pm2[kc * N_TOT + n0 + t] = m2;
    }
}

// ---------------------------------------------------------------------------
// Combine 4 k-chunk partials, emit approx indices + counts, flag uncertain
// rows (m2 within THR of m1). THR = sound bound on |s_fp16 - s_exact|.
__global__ __launch_bounds__(256)
void k_combine2(const float* __restrict__ pv, const int* __restrict__ pi,
                const float* __restrict__ pm2, const float* __restrict__ l1b,
                float* __restrict__ out_idx, float* __restrict__ counts,
                int* __restrict__ flaglist, int* __restrict__ flagn) {
    int n = blockIdx.x * 256 + threadIdx.x;
    float m1 = INFINITY, m2 = INFINITY; int i1 = 0;
#pragma unroll
    for (int c = 0; c < 4; ++c) {
        float a1 = pv [c * N_TOT + n];
        int   ai = pi [c * N_TOT + n];
        float a2 = pm2[c * N_TOT + n];
        if (a1 < m1) { m2 = fminf(m1, a2); m1 = a1; i1 = ai; }
        else         { m2 = fminf(m2, a1); }
    }
    out_idx[n] = (float)i1;
    atomicAdd(counts + i1, 1.0f);
    float thr = l1b[n] * 2.9e-6f + 2.5e-4f;
    if (m2 <= m1 + thr) {
        int p = atomicAdd(flagn, 1);
        flaglist[p] = n;
    }
}

// ---------------------------------------------------------------------------
// Transpose z_e [64][256][1024] -> zflat [65536][256] (into O_ZQ region,
// overwriting the dead fp16/partial scratch; runs BEFORE the rescue so the
// rescue gets coalesced row reads).
__global__ __launch_bounds__(256)
void k_zt(const float* __restrict__ ze, float* __restrict__ zflat) {
    __shared__ float tile[64][65];
    const int t = threadIdx.x;
    const int hw0 = blockIdx.x * 64;
    const int d0  = blockIdx.y * 64;
    const int b   = blockIdx.z;
    const size_t base_in = (size_t)b * (D_DIM * HW_SZ);
#pragma unroll
    for (int p = 0; p < 4; ++p) {
        int dd = p * 16 + (t >> 4);
        int c4 = (t & 15) * 4;
        float4 v = *(const float4*)(ze + base_in + (size_t)(d0 + dd) * HW_SZ + hw0 + c4);
        tile[dd][c4 + 0] = v.x;
        tile[dd][c4 + 1] = v.y;
        tile[dd][c4 + 2] = v.z;
        tile[dd][c4 + 3] = v.w;
    }
    __syncthreads();
#pragma unroll
    for (int p = 0; p < 4; ++p) {
        int hh  = p * 16 + (t >> 4);
        int dc4 = (t & 15) * 4;
        float4 v = { tile[dc4 + 0][hh], tile[dc4 + 1][hh],
                     tile[dc4 + 2][hh], tile[dc4 + 3][hh] };
        *(float4*)(zflat + (size_t)(b * HW_SZ + hw0 + hh) * D_DIM + d0 + dc4) = v;
    }
}

// ---------------------------------------------------------------------------
// Exact rescue v2: register-GEMM over flagged rows only.
// 32 rows/block (8 rows x 16 codes per thread, 128 f32 accumulators), CT rows
// streamed from L2 with 1-deep prefetch, z broadcast from LDS. 3 barriers per
// group (vs ~66 in v1). Arithmetic identical to v1: G = sequential fmaf over
// ascending d; s = fl(zn - 2G) + cn; lexicographic (value, index) min.
__global__ __launch_bounds__(256)
void k_rescue2(const float* __restrict__ zflat, const float* __restrict__ ct,
               const float* __restrict__ cn, const float* __restrict__ znb,
               const int* __restrict__ flaglist, const int* __restrict__ flagn,
               float* __restrict__ out_idx, float* __restrict__ counts) {
    __shared__ float zl[256][36];    // [d][row], pad 36: conflict-light, 16B rows
    __shared__ float cnl[1024];
    __shared__ int rows[32];
    const int t  = threadIdx.x;
    const int tx = t & 63;           // k-group: codes tx*16 .. tx*16+15
    const int ty = t >> 6;           // wave id: rows ty*8 .. ty*8+7
    const int nf = *flagn;
#pragma unroll
    for (int i = 0; i < 4; ++i) cnl[i * 256 + t] = cn[i * 256 + t];

    const float* cbase = ct + tx * 16;

    for (int grp = blockIdx.x; grp * 32 < nf; grp += 2048) {
        __syncthreads();             // prev iteration fully done (zl/rows reuse)
        if (t < 32) {
            int ii = grp * 32 + t;
            rows[t] = flaglist[ii < nf ? ii : nf - 1];
        }
        __syncthreads();
        // stage 32 z rows, coalesced from zflat
        for (int r = 0; r < 32; ++r)
            zl[t][r] = zflat[(size_t)rows[r] * D_DIM + t];
        __syncthreads();

        f2 acc2[8][8];
#pragma unroll
        for (int r = 0; r < 8; ++r)
#pragma unroll
            for (int i = 0; i < 8; ++i) acc2[r][i] = (f2)0.f;

        // prefetch d=0 CT slice
        float4 pa = *(const float4*)(cbase + 0);
        float4 pb = *(const float4*)(cbase + 4);
        float4 pc = *(const float4*)(cbase + 8);
        float4 pd = *(const float4*)(cbase + 12);
#pragma unroll 2
        for (int d = 0; d < 256; ++d) {
            // prefetch next d (d=255 reads 4KB past CT: still inside d_out, harmless)
            const float* q = cbase + (size_t)(d + 1) * K_CODES;
            float4 na = *(const float4*)(q + 0);
            float4 nb = *(const float4*)(q + 4);
            float4 nc = *(const float4*)(q + 8);
            float4 nd = *(const float4*)(q + 12);
            const float* zp = &zl[d][ty * 8];
            float4 z03 = *(const float4*)(zp);
            float4 z47 = *(const float4*)(zp + 4);
            float zzs[8] = { z03.x, z03.y, z03.z, z03.w,
                             z47.x, z47.y, z47.z, z47.w };
            f2 cc2[8] = { { pa.x, pa.y }, { pa.z, pa.w },
                          { pb.x, pb.y }, { pb.z, pb.w },
                          { pc.x, pc.y }, { pc.z, pc.w },
                          { pd.x, pd.y }, { pd.z, pd.w } };
#pragma unroll
            for (int r = 0; r < 8; ++r) {
                f2 zj = { zzs[r], zzs[r] };
#pragma unroll
                for (int i = 0; i < 8; ++i)
                    acc2[r][i] = __builtin_elementwise_fma(zj, cc2[i], acc2[r][i]);
            }
            pa = na; pb = nb; pc = nc; pd = nd;
        }

        // fold + full-wave lexicographic reduce, one row at a time
#pragma unroll
        for (int r = 0; r < 8; ++r) {
            int n = rows[ty * 8 + r];
            float znv = znb[n];
            float bs = INFINITY; int bk = 0;
#pragma unroll
            for (int i2 = 0; i2 < 8; ++i2)
#pragma unroll
                for (int c = 0; c < 2; ++c) {
                    int k = tx * 16 + i2 * 2 + c;
                    float a  = c ? acc2[r][i2].y : acc2[r][i2].x;
                    float tt = znv - 2.0f * a;
                    float s  = tt + cnl[k];
                    if (s < bs || (s == bs && k < bk)) { bs = s; bk = k; }
                }
            for (int off = 1; off < 64; off <<= 1) {
                float os = __shfl_xor(bs, off, 64);
                int   ok = __shfl_xor(bk, off, 64);
                if (os < bs || (os == bs && ok < bk)) { bs = os; bk = ok; }
            }
            if (tx == 0 && grp * 32 + ty * 8 + r < nf) {
                int old = (int)out_idx[n];
                if (old != bk) {
                    out_idx[n] = (float)bk;
                    atomicAdd(counts + old, -1.0f);
                    atomicAdd(counts + bk,  1.0f);
                }
            }
        }
    }
}

// ---------------------------------------------------------------------------
// EMA cluster size + smoothed (loss finalize lives in k_zq).
__global__ __launch_bounds__(1024)
void k_ema_cs(const float* __restrict__ ema_cs, const float* __restrict__ counts,
              float* __restrict__ out_cs, float* __restrict__ smoothed) {
    __shared__ float red[1024];
    int k = threadIdx.x;
    float cs_new = fmaf(0.99f, ema_cs[k], 0.01f * counts[k]);
    red[k] = cs_new;
    __syncthreads();
    for (int off = 512; off > 0; off >>= 1) {
        if (k < off) red[k] += red[k + off];
        __syncthreads();
    }
    float ntot = red[0];
    out_cs[k] = cs_new;
    smoothed[k] = (cs_new + 1e-5f) / (ntot + 0.01024f) * ntot;
}

// ---------------------------------------------------------------------------
// Per-code segment sum: one block per code; compact matching rows into an LDS
// queue, sum rows coalesced from zflat with 2-way load ILP. Fuses loss
// partials + dw EMA + cb write.
__global__ __launch_bounds__(256)
void k_dwsum(const float* __restrict__ idxf, const float* __restrict__ zflat,
             const float* __restrict__ cb, const float* __restrict__ ema_dw,
             const float* __restrict__ smoothed, float* __restrict__ out_dw,
             float* __restrict__ out_cb, float* __restrict__ lossacc) {
    __shared__ int queue[4096];
    __shared__ int qn;
    __shared__ float lred[4];

    const int k = blockIdx.x;
    const int t = threadIdx.x;
    const float fk = (float)k;
    const float ck = cb[(size_t)k * D_DIM + t];

    float acc = 0.f;
    float ls  = 0.f;

    for (int chunk = 0; chunk < 16; ++chunk) {
        if (t == 0) qn = 0;
        __syncthreads();
#pragma unroll
        for (int j = 0; j < 16; ++j) {
            int n = chunk * 4096 + j * 256 + t;        // coalesced idx read
            if (idxf[n] == fk) {
                int p = atomicAdd(&qn, 1);
                queue[p] = n;
            }
        }
        __syncthreads();
        int m = qn;
        int i = 0;
        for (; i + 1 < m; i += 2) {                    // 2-way load ILP
            int n1 = queue[i], n2 = queue[i + 1];
            float z1 = zflat[(size_t)n1 * D_DIM + t];
            float z2 = zflat[(size_t)n2 * D_DIM + t];
            acc += z1; float d1 = ck - z1; ls += d1 * d1;
            acc += z2; float d2 = ck - z2; ls += d2 * d2;
        }
        if (i < m) {
            int n1 = queue[i];
            float z1 = zflat[(size_t)n1 * D_DIM + t];
            acc += z1; float d1 = ck - z1; ls += d1 * d1;
        }
        __syncthreads();   // all queue reads done before next chunk's writes
    }

    size_t o = (size_t)k * D_DIM + t;
    float nd = fmaf(0.99f, ema_dw[o], 0.01f * acc);
    out_dw[o] = nd;
    out_cb[o] = nd / smoothed[k];

#pragma unroll
    for (int off = 32; off > 0; off >>= 1) ls += __shfl_down(ls, off, 64);
    if ((t & 63) == 0) lred[t >> 6] = ls;
    __syncthreads();
    if (t == 0) atomicAdd(lossacc, lred[0] + lred[1] + lred[2] + lred[3]);
}

// ---------------------------------------------------------------------------
// Straight-through z_q writer: pure float4 stream + L2 codebook gather.
// Also finalizes the loss (lossacc complete from k_dwsum, stream-ordered).
__global__ __launch_bounds__(256)
void k_zq(const float* __restrict__ ze, const float* __restrict__ cb,
          const float* __restrict__ idxf, float* __restrict__ out0,
          const float* __restrict__ lossacc, float* __restrict__ out_loss) {
    const int t = threadIdx.x;
    int g   = blockIdx.x * 64 + (t & 63);   // hw4-group id in [0, 16384)
    int b   = g >> 8;
    int hwl = (g & 255) * 4;
    int dg  = t >> 6;                        // d-quarter (0..3)
    const size_t base = (size_t)b * (D_DIM * HW_SZ) + hwl;

    int i0 = (int)idxf[b * HW_SZ + hwl + 0];
    int i1 = (int)idxf[b * HW_SZ + hwl + 1];
    int i2 = (int)idxf[b * HW_SZ + hwl + 2];
    int i3 = (int)idxf[b * HW_SZ + hwl + 3];
    const float* c0 = cb + (size_t)i0 * D_DIM;
    const float* c1 = cb + (size_t)i1 * D_DIM;
    const float* c2 = cb + (size_t)i2 * D_DIM;
    const float* c3 = cb + (size_t)i3 * D_DIM;

#pragma unroll 2
    for (int i = 0; i < 64; ++i) {
        int d = dg * 64 + i;
        size_t o = base + (size_t)d * HW_SZ;
        float4 z = *(const float4*)(ze + o);
        float4 r;
        r.x = z.x + (c0[d] - z.x);
        r.y = z.y + (c1[d] - z.y);
        r.z = z.z + (c2[d] - z.z);
        r.w = z.w + (c3[d] - z.w);
        *(float4*)(out0 + o) = r;
    }

    if (blockIdx.x == 0 && t == 0)
        out_loss[0] = 0.5f * lossacc[0] / ND_TOT;
}

// ---------------------------------------------------------------------------
extern "C" void kernel_launch(void* const* d_in, const int* in_sizes, int n_in,
                              void* d_out, int out_size, void* d_ws, size_t ws_size,
                              hipStream_t stream) {
    const float* ze     = (const float*)d_in[0];  // [64,256,32,32]
    const float* cb     = (const float*)d_in[1];  // [1024,256]
    const float* emacs  = (const float*)d_in[2];  // [1024]
    const float* emadw  = (const float*)d_in[3];  // [1024,256]
    float* out = (float*)d_out;
    float* ws  = (float*)d_ws;

    // Scratch choreography (stream-ordered reuse of d_out):
    //   O_ZQ region: ZH/CH (prep -> margmin), PV/PI/PM2 (margmin -> combine2),
    //     L1 (zn2 -> combine2) — all dead before k_zt writes zflat there;
    //     zflat (zt -> rescue2/dwsum) — overwritten by k_zq at the end.
    //   Tail: CT at O_CB (transpose -> rescue2, then out_cb by dwsum);
    //     ZN + FLAG at O_DW (zn2/combine2 -> rescue2, then out_dw by dwsum).
    f16*   ZH    = (f16*)(out + ZHALF_OFF);
    f16*   CH    = (f16*)(out + CHALF_OFF);
    float* PM2   = out + PM2_OFF;
    float* PV    = out + PV_OFF;
    int*   PI    = (int*)(out + PI_OFF);
    float* L1b   = out + L1_OFF;
    float* ZFLAT = out;
    float* CT    = out + O_CB;
    float* ZNb   = out + O_DW;
    int*   FLAG  = (int*)(out + O_DW + 65536);
    // d_ws scratch
    float* counts   = ws;                 // 1024
    float* lossacc  = ws + 1024;          // 1
    int*   flagn    = (int*)(ws + 1025);  // 1
    float* smoothed = ws + 1088;          // 1024
    float* CN       = ws + 2112;          // 1024

    hipMemsetAsync(ws, 0, 1032 * sizeof(float), stream);

    k_transpose<<<dim3(32, 8), 256, 0, stream>>>(cb, CT);
    k_cnorm<<<4, 256, 0, stream>>>(cb, CN);
    k_zn2<<<256, 256, 0, stream>>>(ze, ZNb, L1b);
    k_prep_c<<<256, 256, 0, stream>>>(cb, CH);
    k_prep_z<<<dim3(16, 4, 64), 256, 0, stream>>>(ze, ZH);
    k_margmin<<<dim3(512, 4), 256, 0, stream>>>(ZH, CH, CN, ZNb, PV, PI, PM2);
    k_combine2<<<256, 256, 0, stream>>>(PV, PI, PM2, L1b, out + O_IDX, counts,
                                        FLAG, flagn);
    k_zt<<<dim3(16, 4, 64), 256, 0, stream>>>(ze, ZFLAT);
    k_rescue2<<<2048, 256, 0, stream>>>(ZFLAT, CT, CN, ZNb, FLAG, flagn,
                                        out + O_IDX, counts);
    k_ema_cs<<<1, 1024, 0, stream>>>(emacs, counts, out + O_CS, smoothed);
    k_dwsum<<<K_CODES, 256, 0, stream>>>(out + O_IDX, ZFLAT, cb, emadw, smoothed,
                                         out + O_DW, out + O_CB, lossacc);
    k_zq<<<256, 256, 0, stream>>>(ze, cb, out + O_IDX, out + O_ZQ,
                                  lossacc, out + O_LOSS);
}

// Round 3
// 477.778 us; speedup vs baseline: 1.4377x; 1.1833x over previous
//
#include <hip/hip_runtime.h>
#include <math.h>

// Problem constants
#define K_CODES   1024
#define D_DIM     256
#define HW_SZ     1024          // 32*32
#define N_TOT     65536         // 64 * 1024
#define ND_TOT    16777216.0f   // N_TOT * D_DIM

// Output layout (float32, concatenated in reference return order)
#define O_ZQ    0
#define O_LOSS  16777216
#define O_IDX   16777217
#define O_CB    16842753
#define O_CS    17104897
#define O_DW    17105921

// Scratch inside the O_ZQ region (float units). ALL dead before k_zt
// overwrites the region with zflat.
#define ZHALF_OFF 0           // 65536x256 f16 = 8388608 floats
#define CHALF_OFF 8388608     // 1024x256 f16  = 131072 floats
#define PM2_OFF   8519680     // 4x65536 f32 second-min partials
#define PV_OFF    8781824     // 4x65536 f32 min partials
#define PI_OFF    9043968     // 4x65536 int argmin partials
#define L1_OFF    9306112     // 65536 f32 row L1 norms (for THR bound)
// Scratch in the output tail (survives k_zt; dead before k_dwsum/k_ema_cs):
//   CT  [256][1024] f32 at out+O_CB  (1 MB; overwritten by out_cb)
//   ZN  65536 f32       at out+O_DW  (overwritten by out_dw)
//   FLG 65536 int       at out+O_DW+65536

typedef float f2 __attribute__((ext_vector_type(2)));
typedef float f32x4 __attribute__((ext_vector_type(4)));
typedef _Float16 f16;
typedef _Float16 f16x8 __attribute__((ext_vector_type(8)));
typedef _Float16 f16x4 __attribute__((ext_vector_type(4)));

// ---------------------------------------------------------------------------
// Transpose codebook [K][D] -> CT [D][K] (for the rescue's register GEMM).
__global__ void k_transpose(const float* __restrict__ cb, float* __restrict__ ct) {
    __shared__ float tile[32][33];
    int k0 = blockIdx.x * 32;
    int d0 = blockIdx.y * 32;
    int c = threadIdx.x & 31, r0 = threadIdx.x >> 5;
#pragma unroll
    for (int p = 0; p < 4; ++p) {
        int r = r0 + p * 8;
        tile[r][c] = cb[(k0 + r) * D_DIM + d0 + c];
    }
    __syncthreads();
#pragma unroll
    for (int p = 0; p < 4; ++p) {
        int r = r0 + p * 8;
        ct[(size_t)(d0 + r) * K_CODES + k0 + c] = tile[c][r];
    }
}

// ---------------------------------------------------------------------------
// Per-code squared norms, numpy-pairwise fp32 semantics (contract OFF).
__global__ void k_cnorm(const float* __restrict__ cb, float* __restrict__ cn) {
#pragma clang fp contract(off)
    int k = blockIdx.x * 256 + threadIdx.x;            // grid = 4 blocks
    const float* row = cb + (size_t)k * D_DIM;
    float s1 = 0.f, s2 = 0.f;
#pragma unroll
    for (int blk = 0; blk < 2; ++blk) {
        const float* p = row + blk * 128;
        float r[8];
#pragma unroll
        for (int j = 0; j < 8; ++j) { float v = p[j]; r[j] = v * v; }
        for (int i = 8; i < 128; i += 8) {
#pragma unroll
            for (int j = 0; j < 8; ++j) { float v = p[i + j]; r[j] = r[j] + v * v; }
        }
        float s = ((r[0] + r[1]) + (r[2] + r[3])) + ((r[4] + r[5]) + (r[6] + r[7]));
        if (blk == 0) s1 = s; else s2 = s;
    }
    cn[k] = s1 + s2;
}

// ---------------------------------------------------------------------------
// Per-row squared norms (bit-identical fold) + L1 norms (feeds THR bound).
__global__ void k_zn2(const float* __restrict__ ze, float* __restrict__ zn,
                      float* __restrict__ l1) {
#pragma clang fp contract(off)
    int n = blockIdx.x * 256 + threadIdx.x;            // grid = 256 blocks
    int b = n >> 10, hw = n & 1023;
    const float* p = ze + (size_t)b * (D_DIM * HW_SZ) + hw;
    float s1 = 0.f, s2 = 0.f, a1 = 0.f;
#pragma unroll
    for (int blk = 0; blk < 2; ++blk) {
        const float* q = p + (size_t)(blk * 128) * HW_SZ;
        float r[8], qa[8];
#pragma unroll
        for (int j = 0; j < 8; ++j) {
            float v = q[(size_t)j * HW_SZ];
            r[j] = v * v; qa[j] = fabsf(v);
        }
        for (int i = 8; i < 128; i += 8) {
#pragma unroll
            for (int j = 0; j < 8; ++j) {
                float v = q[(size_t)(i + j) * HW_SZ];
                r[j] = r[j] + v * v;
                qa[j] = qa[j] + fabsf(v);
            }
        }
        float s = ((r[0] + r[1]) + (r[2] + r[3])) + ((r[4] + r[5]) + (r[6] + r[7]));
        a1 += ((qa[0] + qa[1]) + (qa[2] + qa[3])) + ((qa[4] + qa[5]) + (qa[6] + qa[7]));
        if (blk == 0) s1 = s; else s2 = s;
    }
    zn[n] = s1 + s2;
    l1[n] = a1;
}

// ---------------------------------------------------------------------------
// Codebook -> fp16, scaled by 2^10 (exact pow2; keeps values in [-1,1]).
__global__ __launch_bounds__(256)
void k_prep_c(const float* __restrict__ cb, f16* __restrict__ ch) {
    int i = (blockIdx.x * 256 + threadIdx.x) * 4;      // grid = 256 blocks
    float4 v = *(const float4*)(cb + i);
    f16x4 h;
    h[0] = (f16)(v.x * 1024.0f);
    h[1] = (f16)(v.y * 1024.0f);
    h[2] = (f16)(v.z * 1024.0f);
    h[3] = (f16)(v.w * 1024.0f);
    *(f16x4*)(ch + i) = h;
}

// ---------------------------------------------------------------------------
// z_e [64][256][1024] NCHW -> zhalf [65536][256] row-major fp16.
__global__ __launch_bounds__(256)
void k_prep_z(const float* __restrict__ ze, f16* __restrict__ zh) {
    __shared__ float tile[64][65];
    const int t = threadIdx.x;
    const int hw0 = blockIdx.x * 64;
    const int d0  = blockIdx.y * 64;
    const int b   = blockIdx.z;
    const size_t base_in = (size_t)b * (D_DIM * HW_SZ);
#pragma unroll
    for (int p = 0; p < 4; ++p) {
        int dd = p * 16 + (t >> 4);
        int c4 = (t & 15) * 4;
        float4 v = *(const float4*)(ze + base_in + (size_t)(d0 + dd) * HW_SZ + hw0 + c4);
        tile[dd][c4 + 0] = v.x;
        tile[dd][c4 + 1] = v.y;
        tile[dd][c4 + 2] = v.z;
        tile[dd][c4 + 3] = v.w;
    }
    __syncthreads();
#pragma unroll
    for (int p = 0; p < 4; ++p) {
        int hh  = p * 16 + (t >> 4);
        int dc4 = (t & 15) * 4;
        f16x4 h;
        h[0] = (f16)tile[dc4 + 0][hh];
        h[1] = (f16)tile[dc4 + 1][hh];
        h[2] = (f16)tile[dc4 + 2][hh];
        h[3] = (f16)tile[dc4 + 3][hh];
        *(f16x4*)(zh + (size_t)(b * HW_SZ + hw0 + hh) * D_DIM + d0 + dc4) = h;
    }
}

// ---------------------------------------------------------------------------
// MFMA argmin: grid = (512 n-tiles, 4 k-chunks).
// Emits per-row (min1, argmin, min2) partials; min2 drives the rescue flag.
__global__ __launch_bounds__(256, 2)
void k_margmin(const f16* __restrict__ zh, const f16* __restrict__ ch,
               const float* __restrict__ cn, const float* __restrict__ zn,
               float* __restrict__ pv, int* __restrict__ pi,
               float* __restrict__ pm2) {
    __shared__ __align__(16) f16 Al[128 * 64];   // 16 KB
    __shared__ __align__(16) f16 Bl[256 * 64];   // 32 KB
    const int t  = threadIdx.x;
    const int w  = t >> 6;       // wave (0..3)
    const int l  = t & 63;       // lane
    const int kc = blockIdx.y;   // k-chunk
    const int n0 = blockIdx.x * 128;
    const int rl = l >> 3;       // staging: row-within-8
    const int gg = l & 7;        // staging: granule
    const int gq = l >> 4;       // frag: quarter-wave group
    const int rr = l & 15;       // frag: row/col within frag

    f32x4 acc[8][4];
#pragma unroll
    for (int a = 0; a < 8; ++a)
#pragma unroll
        for (int b = 0; b < 4; ++b) acc[a][b] = (f32x4)0.f;

    for (int d0 = 0; d0 < 256; d0 += 64) {
        __syncthreads();   // previous iteration's frag reads done
        // stage A (z): 128 rows x 64 d, source granule pre-swizzled
#pragma unroll
        for (int i = 0; i < 4; ++i) {
            int row = w * 32 + i * 8 + rl;
            const f16* g = zh + (size_t)(n0 + row) * D_DIM + d0 + 8 * (gg ^ (row & 7));
            __builtin_amdgcn_global_load_lds(
                (const __attribute__((address_space(1))) void*)g,
                (__attribute__((address_space(3))) void*)((char*)Al + (w * 32 + i * 8) * 128),
                16, 0, 0);
        }
        // stage B (codebook): 256 rows x 64 d
#pragma unroll
        for (int i = 0; i < 8; ++i) {
            int row = w * 64 + i * 8 + rl;
            const f16* g = ch + (size_t)(kc * 256 + row) * D_DIM + d0 + 8 * (gg ^ (row & 7));
            __builtin_amdgcn_global_load_lds(
                (const __attribute__((address_space(1))) void*)g,
                (__attribute__((address_space(3))) void*)((char*)Bl + (w * 64 + i * 8) * 128),
                16, 0, 0);
        }
        __syncthreads();
#pragma unroll
        for (int ks = 0; ks < 2; ++ks) {
            f16x8 af[8], bf[4];
#pragma unroll
            for (int nf = 0; nf < 8; ++nf) {
                int row = nf * 16 + rr;
                af[nf] = *(const f16x8*)((char*)Al + row * 128 +
                                         16 * ((ks * 4 + gq) ^ (row & 7)));
            }
#pragma unroll
            for (int kf = 0; kf < 4; ++kf) {
                int row = w * 64 + kf * 16 + rr;
                bf[kf] = *(const f16x8*)((char*)Bl + row * 128 +
                                         16 * ((ks * 4 + gq) ^ (row & 7)));
            }
#pragma unroll
            for (int nf = 0; nf < 8; ++nf)
#pragma unroll
                for (int kf = 0; kf < 4; ++kf)
                    acc[nf][kf] = __builtin_amdgcn_mfma_f32_16x16x32_f16(
                        af[nf], bf[kf], acc[nf][kf], 0, 0, 0);
        }
    }
    __syncthreads();   // all frag reads done before Al reuse

    // Fold + per-row (min1, idx1, min2). D layout: row n = (l>>4)*4 + reg,
    // col k = l&15 (m89-verified C/D mapping).
    float* red = (float*)Al;   // 4 waves x 128 rows x 3 floats = 6 KB
    float cnv[4];
#pragma unroll
    for (int kf = 0; kf < 4; ++kf)
        cnv[kf] = cn[kc * 256 + w * 64 + kf * 16 + rr];
#pragma unroll
    for (int nf = 0; nf < 8; ++nf) {
#pragma unroll
        for (int r = 0; r < 4; ++r) {
            float znv = zn[n0 + nf * 16 + gq * 4 + r];
            float m1 = INFINITY, m2 = INFINITY; int i1 = 0;
#pragma unroll
            for (int kf = 0; kf < 4; ++kf) {
                float g  = acc[nf][kf][r] * 0x1p-10f;  // undo codebook scale (exact)
                float tt = znv - 2.0f * g;
                float s  = tt + cnv[kf];
                int k = kc * 256 + w * 64 + kf * 16 + rr;
                if (s < m1) { m2 = m1; m1 = s; i1 = k; }
                else        { m2 = fminf(m2, s); }
            }
            // reduce across the 16 lanes holding this row's 64 k values
            for (int off = 1; off < 16; off <<= 1) {
                float o1 = __shfl_xor(m1, off, 64);
                float o2 = __shfl_xor(m2, off, 64);
                int   oi = __shfl_xor(i1, off, 64);
                if (o1 < m1) { m2 = fminf(m1, o2); m1 = o1; i1 = oi; }
                else         { m2 = fminf(m2, o1); }
            }
            if (rr == 0) {
                int nl = nf * 16 + gq * 4 + r;
                red[(w * 128 + nl) * 3 + 0] = m1;
                red[(w * 128 + nl) * 3 + 1] = __int_as_float(i1);
                red[(w * 128 + nl) * 3 + 2] = m2;
            }
        }
    }
    __syncthreads();
    if (t < 128) {
        float m1 = INFINITY, m2 = INFINITY; int i1 = 0;
#pragma unroll
        for (int w2 = 0; w2 < 4; ++w2) {
            float a1 = red[(w2 * 128 + t) * 3 + 0];
            int   ai = __float_as_int(red[(w2 * 128 + t) * 3 + 1]);
            float a2 = red[(w2 * 128 + t) * 3 + 2];
            if (a1 < m1) { m2 = fminf(m1, a2); m1 = a1; i1 = ai; }
            else         { m2 = fminf(m2, a1); }
        }
        pv [kc * N_TOT + n0 + t] = m1;
        pi [kc * N_TOT + n0 + t] = i1;
        pm2[kc * N_TOT + n0 + t] = m2;
    }
}

// ---------------------------------------------------------------------------
// Combine 4 k-chunk partials, emit approx indices + counts, flag uncertain
// rows (m2 within THR of m1). THR = sound bound on |s_fp16 - s_exact|.
__global__ __launch_bounds__(256)
void k_combine2(const float* __restrict__ pv, const int* __restrict__ pi,
                const float* __restrict__ pm2, const float* __restrict__ l1b,
                float* __restrict__ out_idx, float* __restrict__ counts,
                int* __restrict__ flaglist, int* __restrict__ flagn) {
    int n = blockIdx.x * 256 + threadIdx.x;
    float m1 = INFINITY, m2 = INFINITY; int i1 = 0;
#pragma unroll
    for (int c = 0; c < 4; ++c) {
        float a1 = pv [c * N_TOT + n];
        int   ai = pi [c * N_TOT + n];
        float a2 = pm2[c * N_TOT + n];
        if (a1 < m1) { m2 = fminf(m1, a2); m1 = a1; i1 = ai; }
        else         { m2 = fminf(m2, a1); }
    }
    out_idx[n] = (float)i1;
    atomicAdd(counts + i1, 1.0f);
    float thr = l1b[n] * 2.9e-6f + 2.5e-4f;
    if (m2 <= m1 + thr) {
        int p = atomicAdd(flagn, 1);
        flaglist[p] = n;
    }
}

// ---------------------------------------------------------------------------
// Transpose z_e [64][256][1024] -> zflat [65536][256] (into O_ZQ region,
// overwriting the dead fp16/partial scratch; runs BEFORE the rescue so the
// rescue gets coalesced row reads).
__global__ __launch_bounds__(256)
void k_zt(const float* __restrict__ ze, float* __restrict__ zflat) {
    __shared__ float tile[64][65];
    const int t = threadIdx.x;
    const int hw0 = blockIdx.x * 64;
    const int d0  = blockIdx.y * 64;
    const int b   = blockIdx.z;
    const size_t base_in = (size_t)b * (D_DIM * HW_SZ);
#pragma unroll
    for (int p = 0; p < 4; ++p) {
        int dd = p * 16 + (t >> 4);
        int c4 = (t & 15) * 4;
        float4 v = *(const float4*)(ze + base_in + (size_t)(d0 + dd) * HW_SZ + hw0 + c4);
        tile[dd][c4 + 0] = v.x;
        tile[dd][c4 + 1] = v.y;
        tile[dd][c4 + 2] = v.z;
        tile[dd][c4 + 3] = v.w;
    }
    __syncthreads();
#pragma unroll
    for (int p = 0; p < 4; ++p) {
        int hh  = p * 16 + (t >> 4);
        int dc4 = (t & 15) * 4;
        float4 v = { tile[dc4 + 0][hh], tile[dc4 + 1][hh],
                     tile[dc4 + 2][hh], tile[dc4 + 3][hh] };
        *(float4*)(zflat + (size_t)(b * HW_SZ + hw0 + hh) * D_DIM + d0 + dc4) = v;
    }
}

// ---------------------------------------------------------------------------
// Exact rescue v3: parallelism-first reshape.
// 8 rows/block (4 waves); wave w owns codes [w*256,(w+1)*256) for ALL 8 rows
// -> 32 acc/thread (no spill), ~nf/8 active blocks (~1/CU at nf~2K) with a
// 4-deep software-pipelined CT prefetch to cover L2 latency.
// Arithmetic identical to v2: per (row,code) dot = sequential pk-fma over
// ascending d; s = fl(zn - 2G) + cn; lexicographic (value, index) min
// (thread -> lane-shuffle -> cross-wave merge in ascending-k order).
__global__ __launch_bounds__(256)
void k_rescue3(const float* __restrict__ zflat, const float* __restrict__ ct,
               const float* __restrict__ cn, const float* __restrict__ znb,
               const int* __restrict__ flaglist, const int* __restrict__ flagn,
               float* __restrict__ out_idx, float* __restrict__ counts) {
    __shared__ float zl[8][256];     // [row][d]; broadcast reads
    __shared__ float znl[8];
    __shared__ float cnl[1024];
    __shared__ float redv[4][8];
    __shared__ int   redi[4][8];
    __shared__ int   rows[8];
    const int t  = threadIdx.x;
    const int w  = t >> 6;           // wave: codes w*256 .. w*256+255
    const int tx = t & 63;           // lane: codes w*256 + tx*4 .. +3
    const int nf = *flagn;
#pragma unroll
    for (int i = 0; i < 4; ++i) cnl[i * 256 + t] = cn[i * 256 + t];

    const float* cbase = ct + w * 256 + tx * 4;
    const int kbase = w * 256 + tx * 4;

#define LD(i) (*(const float4*)(cbase + (size_t)(i) * K_CODES))

    for (int grp = blockIdx.x; grp * 8 < nf; grp += 1024) {
        __syncthreads();             // prev group fully done (zl/rows reuse)
        if (t < 8) {
            int ii = grp * 8 + t;
            int n = flaglist[ii < nf ? ii : nf - 1];
            rows[t] = n;
            znl[t] = znb[n];
        }
        __syncthreads();
        // stage 8 z rows, coalesced from zflat
#pragma unroll
        for (int r = 0; r < 8; ++r)
            zl[r][t] = zflat[(size_t)rows[r] * D_DIM + t];
        __syncthreads();

        f2 acc2[8][2];
#pragma unroll
        for (int r = 0; r < 8; ++r) { acc2[r][0] = (f2)0.f; acc2[r][1] = (f2)0.f; }

        float4 p0 = LD(0), p1 = LD(1), p2 = LD(2), p3 = LD(3);
        for (int d = 0; d < 256; d += 4) {
            float4 zr[8];
#pragma unroll
            for (int r = 0; r < 8; ++r)
                zr[r] = *(const float4*)&zl[r][d];
            // d+0
#pragma unroll
            for (int r = 0; r < 8; ++r) {
                f2 zj = { zr[r].x, zr[r].x };
                acc2[r][0] = __builtin_elementwise_fma(zj, (f2){p0.x, p0.y}, acc2[r][0]);
                acc2[r][1] = __builtin_elementwise_fma(zj, (f2){p0.z, p0.w}, acc2[r][1]);
            }
            p0 = LD(d + 4);          // reads <= row 259: 3 rows past CT, in-bounds of d_out
            // d+1
#pragma unroll
            for (int r = 0; r < 8; ++r) {
                f2 zj = { zr[r].y, zr[r].y };
                acc2[r][0] = __builtin_elementwise_fma(zj, (f2){p1.x, p1.y}, acc2[r][0]);
                acc2[r][1] = __builtin_elementwise_fma(zj, (f2){p1.z, p1.w}, acc2[r][1]);
            }
            p1 = LD(d + 5);
            // d+2
#pragma unroll
            for (int r = 0; r < 8; ++r) {
                f2 zj = { zr[r].z, zr[r].z };
                acc2[r][0] = __builtin_elementwise_fma(zj, (f2){p2.x, p2.y}, acc2[r][0]);
                acc2[r][1] = __builtin_elementwise_fma(zj, (f2){p2.z, p2.w}, acc2[r][1]);
            }
            p2 = LD(d + 6);
            // d+3
#pragma unroll
            for (int r = 0; r < 8; ++r) {
                f2 zj = { zr[r].w, zr[r].w };
                acc2[r][0] = __builtin_elementwise_fma(zj, (f2){p3.x, p3.y}, acc2[r][0]);
                acc2[r][1] = __builtin_elementwise_fma(zj, (f2){p3.z, p3.w}, acc2[r][1]);
            }
            p3 = LD(d + 7);
        }

        // fold + reduce, one row at a time
#pragma unroll
        for (int r = 0; r < 8; ++r) {
            float znv = znl[r];
            float bs = INFINITY; int bk = 0;
            float a0 = acc2[r][0].x, a1 = acc2[r][0].y;
            float a2 = acc2[r][1].x, a3 = acc2[r][1].y;
            {
                float s0 = (znv - 2.0f * a0) + cnl[kbase + 0];
                float s1 = (znv - 2.0f * a1) + cnl[kbase + 1];
                float s2 = (znv - 2.0f * a2) + cnl[kbase + 2];
                float s3 = (znv - 2.0f * a3) + cnl[kbase + 3];
                bs = s0; bk = kbase;
                if (s1 < bs) { bs = s1; bk = kbase + 1; }
                if (s2 < bs) { bs = s2; bk = kbase + 2; }
                if (s3 < bs) { bs = s3; bk = kbase + 3; }
            }
            for (int off = 1; off < 64; off <<= 1) {
                float os = __shfl_xor(bs, off, 64);
                int   ok = __shfl_xor(bk, off, 64);
                if (os < bs || (os == bs && ok < bk)) { bs = os; bk = ok; }
            }
            if (tx == 0) { redv[w][r] = bs; redi[w][r] = bk; }
        }
        __syncthreads();
        if (t < 8 && grp * 8 + t < nf) {
            float bs = redv[0][t]; int bk = redi[0][t];
#pragma unroll
            for (int w2 = 1; w2 < 4; ++w2) {
                float os = redv[w2][t];   // ascending wave = ascending k
                int   ok = redi[w2][t];
                if (os < bs) { bs = os; bk = ok; }
            }
            int n = rows[t];
            int old = (int)out_idx[n];
            if (old != bk) {
                out_idx[n] = (float)bk;
                atomicAdd(counts + old, -1.0f);
                atomicAdd(counts + bk,  1.0f);
            }
        }
    }
#undef LD
}

// ---------------------------------------------------------------------------
// EMA cluster size + smoothed (loss finalize lives in k_zq).
__global__ __launch_bounds__(1024)
void k_ema_cs(const float* __restrict__ ema_cs, const float* __restrict__ counts,
              float* __restrict__ out_cs, float* __restrict__ smoothed) {
    __shared__ float red[1024];
    int k = threadIdx.x;
    float cs_new = fmaf(0.99f, ema_cs[k], 0.01f * counts[k]);
    red[k] = cs_new;
    __syncthreads();
    for (int off = 512; off > 0; off >>= 1) {
        if (k < off) red[k] += red[k + off];
        __syncthreads();
    }
    float ntot = red[0];
    out_cs[k] = cs_new;
    smoothed[k] = (cs_new + 1e-5f) / (ntot + 0.01024f) * ntot;
}

// ---------------------------------------------------------------------------
// Per-code segment sum: one block per code; compact matching rows into an LDS
// queue (float4 index scan: 4x fewer scan loads), sum rows coalesced from
// zflat with 2-way load ILP. Fuses loss partials + dw EMA + cb write.
__global__ __launch_bounds__(256)
void k_dwsum(const float* __restrict__ idxf, const float* __restrict__ zflat,
             const float* __restrict__ cb, const float* __restrict__ ema_dw,
             const float* __restrict__ smoothed, float* __restrict__ out_dw,
             float* __restrict__ out_cb, float* __restrict__ lossacc) {
    __shared__ int queue[4096];
    __shared__ int qn;
    __shared__ float lred[4];

    const int k = blockIdx.x;
    const int t = threadIdx.x;
    const float fk = (float)k;
    const float ck = cb[(size_t)k * D_DIM + t];

    float acc = 0.f;
    float ls  = 0.f;

    for (int chunk = 0; chunk < 16; ++chunk) {
        if (t == 0) qn = 0;
        __syncthreads();
#pragma unroll
        for (int j = 0; j < 4; ++j) {
            int nb = chunk * 4096 + j * 1024 + t * 4;   // coalesced float4 scan
            float4 iv = *(const float4*)(idxf + nb);
            if (iv.x == fk) { int p = atomicAdd(&qn, 1); queue[p] = nb; }
            if (iv.y == fk) { int p = atomicAdd(&qn, 1); queue[p] = nb + 1; }
            if (iv.z == fk) { int p = atomicAdd(&qn, 1); queue[p] = nb + 2; }
            if (iv.w == fk) { int p = atomicAdd(&qn, 1); queue[p] = nb + 3; }
        }
        __syncthreads();
        int m = qn;
        int i = 0;
        for (; i + 1 < m; i += 2) {                    // 2-way load ILP
            int n1 = queue[i], n2 = queue[i + 1];
            float z1 = zflat[(size_t)n1 * D_DIM + t];
            float z2 = zflat[(size_t)n2 * D_DIM + t];
            acc += z1; float d1 = ck - z1; ls += d1 * d1;
            acc += z2; float d2 = ck - z2; ls += d2 * d2;
        }
        if (i < m) {
            int n1 = queue[i];
            float z1 = zflat[(size_t)n1 * D_DIM + t];
            acc += z1; float d1 = ck - z1; ls += d1 * d1;
        }
        __syncthreads();   // all queue reads done before next chunk's writes
    }

    size_t o = (size_t)k * D_DIM + t;
    float nd = fmaf(0.99f, ema_dw[o], 0.01f * acc);
    out_dw[o] = nd;
    out_cb[o] = nd / smoothed[k];

#pragma unroll
    for (int off = 32; off > 0; off >>= 1) ls += __shfl_down(ls, off, 64);
    if ((t & 63) == 0) lred[t >> 6] = ls;
    __syncthreads();
    if (t == 0) atomicAdd(lossacc, lred[0] + lred[1] + lred[2] + lred[3]);
}

// ---------------------------------------------------------------------------
// Straight-through z_q writer: pure float4 stream + L2 codebook gather.
// Also finalizes the loss (lossacc complete from k_dwsum, stream-ordered).
__global__ __launch_bounds__(256)
void k_zq(const float* __restrict__ ze, const float* __restrict__ cb,
          const float* __restrict__ idxf, float* __restrict__ out0,
          const float* __restrict__ lossacc, float* __restrict__ out_loss) {
    const int t = threadIdx.x;
    int g   = blockIdx.x * 64 + (t & 63);   // hw4-group id in [0, 16384)
    int b   = g >> 8;
    int hwl = (g & 255) * 4;
    int dg  = t >> 6;                        // d-quarter (0..3)
    const size_t base = (size_t)b * (D_DIM * HW_SZ) + hwl;

    int i0 = (int)idxf[b * HW_SZ + hwl + 0];
    int i1 = (int)idxf[b * HW_SZ + hwl + 1];
    int i2 = (int)idxf[b * HW_SZ + hwl + 2];
    int i3 = (int)idxf[b * HW_SZ + hwl + 3];
    const float* c0 = cb + (size_t)i0 * D_DIM;
    const float* c1 = cb + (size_t)i1 * D_DIM;
    const float* c2 = cb + (size_t)i2 * D_DIM;
    const float* c3 = cb + (size_t)i3 * D_DIM;

#pragma unroll 2
    for (int i = 0; i < 64; ++i) {
        int d = dg * 64 + i;
        size_t o = base + (size_t)d * HW_SZ;
        float4 z = *(const float4*)(ze + o);
        float4 r;
        r.x = z.x + (c0[d] - z.x);
        r.y = z.y + (c1[d] - z.y);
        r.z = z.z + (c2[d] - z.z);
        r.w = z.w + (c3[d] - z.w);
        *(float4*)(out0 + o) = r;
    }

    if (blockIdx.x == 0 && t == 0)
        out_loss[0] = 0.5f * lossacc[0] / ND_TOT;
}

// ---------------------------------------------------------------------------
extern "C" void kernel_launch(void* const* d_in, const int* in_sizes, int n_in,
                              void* d_out, int out_size, void* d_ws, size_t ws_size,
                              hipStream_t stream) {
    const float* ze     = (const float*)d_in[0];  // [64,256,32,32]
    const float* cb     = (const float*)d_in[1];  // [1024,256]
    const float* emacs  = (const float*)d_in[2];  // [1024]
    const float* emadw  = (const float*)d_in[3];  // [1024,256]
    float* out = (float*)d_out;
    float* ws  = (float*)d_ws;

    // Scratch choreography (stream-ordered reuse of d_out):
    //   O_ZQ region: ZH/CH (prep -> margmin), PV/PI/PM2 (margmin -> combine2),
    //     L1 (zn2 -> combine2) — all dead before k_zt writes zflat there;
    //     zflat (zt -> rescue3/dwsum) — overwritten by k_zq at the end.
    //   Tail: CT at O_CB (transpose -> rescue3, then out_cb by dwsum);
    //     ZN + FLAG at O_DW (zn2/combine2 -> rescue3, then out_dw by dwsum).
    f16*   ZH    = (f16*)(out + ZHALF_OFF);
    f16*   CH    = (f16*)(out + CHALF_OFF);
    float* PM2   = out + PM2_OFF;
    float* PV    = out + PV_OFF;
    int*   PI    = (int*)(out + PI_OFF);
    float* L1b   = out + L1_OFF;
    float* ZFLAT = out;
    float* CT    = out + O_CB;
    float* ZNb   = out + O_DW;
    int*   FLAG  = (int*)(out + O_DW + 65536);
    // d_ws scratch
    float* counts   = ws;                 // 1024
    float* lossacc  = ws + 1024;          // 1
    int*   flagn    = (int*)(ws + 1025);  // 1
    float* smoothed = ws + 1088;          // 1024
    float* CN       = ws + 2112;          // 1024

    hipMemsetAsync(ws, 0, 1032 * sizeof(float), stream);

    k_transpose<<<dim3(32, 8), 256, 0, stream>>>(cb, CT);
    k_cnorm<<<4, 256, 0, stream>>>(cb, CN);
    k_zn2<<<256, 256, 0, stream>>>(ze, ZNb, L1b);
    k_prep_c<<<256, 256, 0, stream>>>(cb, CH);
    k_prep_z<<<dim3(16, 4, 64), 256, 0, stream>>>(ze, ZH);
    k_margmin<<<dim3(512, 4), 256, 0, stream>>>(ZH, CH, CN, ZNb, PV, PI, PM2);
    k_combine2<<<256, 256, 0, stream>>>(PV, PI, PM2, L1b, out + O_IDX, counts,
                                        FLAG, flagn);
    k_zt<<<dim3(16, 4, 64), 256, 0, stream>>>(ze, ZFLAT);
    k_rescue3<<<1024, 256, 0, stream>>>(ZFLAT, CT, CN, ZNb, FLAG, flagn,
                                        out + O_IDX, counts);
    k_ema_cs<<<1, 1024, 0, stream>>>(emacs, counts, out + O_CS, smoothed);
    k_dwsum<<<K_CODES, 256, 0, stream>>>(out + O_IDX, ZFLAT, cb, emadw, smoothed,
                                         out + O_DW, out + O_CB, lossacc);
    k_zq<<<256, 256, 0, stream>>>(ze, cb, out + O_IDX, out + O_ZQ,
                                  lossacc, out + O_LOSS);
}

// Round 4
// 460.635 us; speedup vs baseline: 1.4912x; 1.0372x over previous
//
#include <hip/hip_runtime.h>
#include <math.h>

// Problem constants
#define K_CODES   1024
#define D_DIM     256
#define HW_SZ     1024          // 32*32
#define N_TOT     65536         // 64 * 1024
#define ND_TOT    16777216.0f   // N_TOT * D_DIM

// Output layout (float32, concatenated in reference return order)
#define O_ZQ    0
#define O_LOSS  16777216
#define O_IDX   16777217
#define O_CB    16842753
#define O_CS    17104897
#define O_DW    17105921

// Scratch inside the O_ZQ region (float units). ALL dead before k_zt
// overwrites the region with zflat.
#define ZHALF_OFF 0           // 65536x256 f16 = 8388608 floats
#define CHALF_OFF 8388608     // 1024x256 f16  = 131072 floats
#define PK2_OFF   8519680     // 4x65536 i32 second-min key partials
#define PK1_OFF   8781824     // 4x65536 i32 min key partials
#define L1_OFF    9306112     // 65536 f32 row L1 norms (for THR bound)
// Scratch in the output tail (survives k_zt; dead before k_dwsum/k_ema_cs):
//   CT  [256][1024] f32 at out+O_CB  (1 MB; overwritten by out_cb)
//   ZN  65536 f32       at out+O_DW  (overwritten by out_dw)
//   FLG 65536 int       at out+O_DW+65536

typedef float f2 __attribute__((ext_vector_type(2)));
typedef float f32x4 __attribute__((ext_vector_type(4)));
typedef _Float16 f16;
typedef _Float16 f16x8 __attribute__((ext_vector_type(8)));
typedef _Float16 f16x4 __attribute__((ext_vector_type(4)));

__device__ __forceinline__ int imin(int a, int b) { return a < b ? a : b; }
__device__ __forceinline__ int imax(int a, int b) { return a > b ? a : b; }

// ---------------------------------------------------------------------------
// Transpose codebook [K][D] -> CT [D][K] (for the rescue's register GEMM).
__global__ void k_transpose(const float* __restrict__ cb, float* __restrict__ ct) {
    __shared__ float tile[32][33];
    int k0 = blockIdx.x * 32;
    int d0 = blockIdx.y * 32;
    int c = threadIdx.x & 31, r0 = threadIdx.x >> 5;
#pragma unroll
    for (int p = 0; p < 4; ++p) {
        int r = r0 + p * 8;
        tile[r][c] = cb[(k0 + r) * D_DIM + d0 + c];
    }
    __syncthreads();
#pragma unroll
    for (int p = 0; p < 4; ++p) {
        int r = r0 + p * 8;
        ct[(size_t)(d0 + r) * K_CODES + k0 + c] = tile[c][r];
    }
}

// ---------------------------------------------------------------------------
// Per-code squared norms, numpy-pairwise fp32 semantics (contract OFF).
__global__ void k_cnorm(const float* __restrict__ cb, float* __restrict__ cn) {
#pragma clang fp contract(off)
    int k = blockIdx.x * 256 + threadIdx.x;            // grid = 4 blocks
    const float* row = cb + (size_t)k * D_DIM;
    float s1 = 0.f, s2 = 0.f;
#pragma unroll
    for (int blk = 0; blk < 2; ++blk) {
        const float* p = row + blk * 128;
        float r[8];
#pragma unroll
        for (int j = 0; j < 8; ++j) { float v = p[j]; r[j] = v * v; }
        for (int i = 8; i < 128; i += 8) {
#pragma unroll
            for (int j = 0; j < 8; ++j) { float v = p[i + j]; r[j] = r[j] + v * v; }
        }
        float s = ((r[0] + r[1]) + (r[2] + r[3])) + ((r[4] + r[5]) + (r[6] + r[7]));
        if (blk == 0) s1 = s; else s2 = s;
    }
    cn[k] = s1 + s2;
}

// ---------------------------------------------------------------------------
// Per-row squared norms (bit-identical fold) + L1 norms (feeds THR bound).
__global__ void k_zn2(const float* __restrict__ ze, float* __restrict__ zn,
                      float* __restrict__ l1) {
#pragma clang fp contract(off)
    int n = blockIdx.x * 256 + threadIdx.x;            // grid = 256 blocks
    int b = n >> 10, hw = n & 1023;
    const float* p = ze + (size_t)b * (D_DIM * HW_SZ) + hw;
    float s1 = 0.f, s2 = 0.f, a1 = 0.f;
#pragma unroll
    for (int blk = 0; blk < 2; ++blk) {
        const float* q = p + (size_t)(blk * 128) * HW_SZ;
        float r[8], qa[8];
#pragma unroll
        for (int j = 0; j < 8; ++j) {
            float v = q[(size_t)j * HW_SZ];
            r[j] = v * v; qa[j] = fabsf(v);
        }
        for (int i = 8; i < 128; i += 8) {
#pragma unroll
            for (int j = 0; j < 8; ++j) {
                float v = q[(size_t)(i + j) * HW_SZ];
                r[j] = r[j] + v * v;
                qa[j] = qa[j] + fabsf(v);
            }
        }
        float s = ((r[0] + r[1]) + (r[2] + r[3])) + ((r[4] + r[5]) + (r[6] + r[7]));
        a1 += ((qa[0] + qa[1]) + (qa[2] + qa[3])) + ((qa[4] + qa[5]) + (qa[6] + qa[7]));
        if (blk == 0) s1 = s; else s2 = s;
    }
    zn[n] = s1 + s2;
    l1[n] = a1;
}

// ---------------------------------------------------------------------------
// Codebook -> fp16, scaled by 2^10 (exact pow2; keeps values in [-1,1]).
__global__ __launch_bounds__(256)
void k_prep_c(const float* __restrict__ cb, f16* __restrict__ ch) {
    int i = (blockIdx.x * 256 + threadIdx.x) * 4;      // grid = 256 blocks
    float4 v = *(const float4*)(cb + i);
    f16x4 h;
    h[0] = (f16)(v.x * 1024.0f);
    h[1] = (f16)(v.y * 1024.0f);
    h[2] = (f16)(v.z * 1024.0f);
    h[3] = (f16)(v.w * 1024.0f);
    *(f16x4*)(ch + i) = h;
}

// ---------------------------------------------------------------------------
// z_e [64][256][1024] NCHW -> zhalf [65536][256] row-major fp16.
__global__ __launch_bounds__(256)
void k_prep_z(const float* __restrict__ ze, f16* __restrict__ zh) {
    __shared__ float tile[64][65];
    const int t = threadIdx.x;
    const int hw0 = blockIdx.x * 64;
    const int d0  = blockIdx.y * 64;
    const int b   = blockIdx.z;
    const size_t base_in = (size_t)b * (D_DIM * HW_SZ);
#pragma unroll
    for (int p = 0; p < 4; ++p) {
        int dd = p * 16 + (t >> 4);
        int c4 = (t & 15) * 4;
        float4 v = *(const float4*)(ze + base_in + (size_t)(d0 + dd) * HW_SZ + hw0 + c4);
        tile[dd][c4 + 0] = v.x;
        tile[dd][c4 + 1] = v.y;
        tile[dd][c4 + 2] = v.z;
        tile[dd][c4 + 3] = v.w;
    }
    __syncthreads();
#pragma unroll
    for (int p = 0; p < 4; ++p) {
        int hh  = p * 16 + (t >> 4);
        int dc4 = (t & 15) * 4;
        f16x4 h;
        h[0] = (f16)tile[dc4 + 0][hh];
        h[1] = (f16)tile[dc4 + 1][hh];
        h[2] = (f16)tile[dc4 + 2][hh];
        h[3] = (f16)tile[dc4 + 3][hh];
        *(f16x4*)(zh + (size_t)(b * HW_SZ + hw0 + hh) * D_DIM + d0 + dc4) = h;
    }
}

// ---------------------------------------------------------------------------
// MFMA argmin: grid = (512 n-tiles, 4 k-chunks). Main loop unchanged.
// NEW epilogue: i32 packed keys. t = cn - 2G (zn dropped: constant per row,
// order-preserving); key = ((int)(t*2^21) << 10) | k. min1/min2/argmin via
// v_min_i32/v_max_i32; one xor-step + LDS scan replaces the 4-step butterfly.
// Emits per-row (key1, key2) partials; key gap drives the rescue flag.
__global__ __launch_bounds__(256, 2)
void k_margmin(const f16* __restrict__ zh, const f16* __restrict__ ch,
               const float* __restrict__ cn,
               int* __restrict__ pk1, int* __restrict__ pk2) {
    __shared__ __align__(16) char smem[49152];
    f16* Al = (f16*)smem;               // [128*64] 16 KB
    f16* Bl = (f16*)(smem + 16384);     // [256*64] 32 KB
    const int t  = threadIdx.x;
    const int w  = t >> 6;       // wave (0..3)
    const int l  = t & 63;       // lane
    const int kc = blockIdx.y;   // k-chunk
    const int n0 = blockIdx.x * 128;
    const int rl = l >> 3;       // staging: row-within-8
    const int gg = l & 7;        // staging: granule
    const int gq = l >> 4;       // frag: quarter-wave group
    const int rr = l & 15;       // frag: row/col within frag

    f32x4 acc[8][4];
#pragma unroll
    for (int a = 0; a < 8; ++a)
#pragma unroll
        for (int b = 0; b < 4; ++b) acc[a][b] = (f32x4)0.f;

    for (int d0 = 0; d0 < 256; d0 += 64) {
        __syncthreads();   // previous iteration's frag reads done
        // stage A (z): 128 rows x 64 d, source granule pre-swizzled
#pragma unroll
        for (int i = 0; i < 4; ++i) {
            int row = w * 32 + i * 8 + rl;
            const f16* g = zh + (size_t)(n0 + row) * D_DIM + d0 + 8 * (gg ^ (row & 7));
            __builtin_amdgcn_global_load_lds(
                (const __attribute__((address_space(1))) void*)g,
                (__attribute__((address_space(3))) void*)(smem + (w * 32 + i * 8) * 128),
                16, 0, 0);
        }
        // stage B (codebook): 256 rows x 64 d
#pragma unroll
        for (int i = 0; i < 8; ++i) {
            int row = w * 64 + i * 8 + rl;
            const f16* g = ch + (size_t)(kc * 256 + row) * D_DIM + d0 + 8 * (gg ^ (row & 7));
            __builtin_amdgcn_global_load_lds(
                (const __attribute__((address_space(1))) void*)g,
                (__attribute__((address_space(3))) void*)(smem + 16384 + row * 128),
                16, 0, 0);
        }
        __syncthreads();
#pragma unroll
        for (int ks = 0; ks < 2; ++ks) {
            f16x8 af[8], bf[4];
#pragma unroll
            for (int nf = 0; nf < 8; ++nf) {
                int row = nf * 16 + rr;
                af[nf] = *(const f16x8*)((char*)Al + row * 128 +
                                         16 * ((ks * 4 + gq) ^ (row & 7)));
            }
#pragma unroll
            for (int kf = 0; kf < 4; ++kf) {
                int row = w * 64 + kf * 16 + rr;
                bf[kf] = *(const f16x8*)((char*)Bl + row * 128 +
                                         16 * ((ks * 4 + gq) ^ (row & 7)));
            }
#pragma unroll
            for (int nf = 0; nf < 8; ++nf)
#pragma unroll
                for (int kf = 0; kf < 4; ++kf)
                    acc[nf][kf] = __builtin_amdgcn_mfma_f32_16x16x32_f16(
                        af[nf], bf[kf], acc[nf][kf], 0, 0, 0);
        }
    }
    __syncthreads();   // all frag reads done before smem reuse

    // Epilogue: packed i32 keys. acc = 1024*G (codebook pre-scale), so
    // t*2^21 = cn*2^21 - acc*2^12.  |t| <= 0.49 -> |tq| < 2^21, key fits i32.
    int* ep = (int*)smem;   // [128][66] ints = 33.8 KB
    float cnq[4];
    int   kk4[4];
#pragma unroll
    for (int kf = 0; kf < 4; ++kf) {
        int k = kc * 256 + w * 64 + kf * 16 + rr;
        kk4[kf] = k;
        cnq[kf] = cn[k] * 0x1p21f;
    }
#pragma unroll
    for (int nf = 0; nf < 8; ++nf) {
#pragma unroll
        for (int r = 0; r < 4; ++r) {
            int m1 = 0x7FFFFFFF, m2 = 0x7FFFFFFF;
#pragma unroll
            for (int kf = 0; kf < 4; ++kf) {
                float tqf = fmaf(acc[nf][kf][r], -0x1p12f, cnq[kf]);
                int key = ((int)tqf << 10) + kk4[kf];
                int mx = imax(m1, key);
                m1 = imin(m1, key);
                m2 = imin(m2, mx);
            }
            // one xor-step: merge lane pairs (rr even|odd)
            int o1 = __shfl_xor(m1, 1, 64);
            int o2 = __shfl_xor(m2, 1, 64);
            int mx = imax(m1, o1);
            m1 = imin(m1, o1);
            m2 = imin(imin(m2, o2), mx);
            if ((rr & 1) == 0) {
                int row = nf * 16 + gq * 4 + r;
                int p   = w * 8 + (rr >> 1);
                *(int2*)&ep[row * 66 + p * 2] = make_int2(m1, m2);
            }
        }
    }
    __syncthreads();
    if (t < 128) {
        int m1 = 0x7FFFFFFF, m2 = 0x7FFFFFFF;
        const int2* rp = (const int2*)&ep[t * 66];
#pragma unroll 8
        for (int p = 0; p < 32; ++p) {
            int2 a = rp[p];
            int mx = imax(m1, a.x);
            m1 = imin(m1, a.x);
            m2 = imin(imin(m2, a.y), mx);
        }
        pk1[kc * N_TOT + n0 + t] = m1;
        pk2[kc * N_TOT + n0 + t] = m2;
    }
}

// ---------------------------------------------------------------------------
// Combine 4 k-chunk key partials, emit approx indices + counts, flag rows
// whose dequantized key gap is within THR (sound bound on |t_fp16 - t_exact|:
// fp16 term l1*2.9e-6, zn-deferral reorder <=8e-5, quantization ~1e-6, plus
// the old constant; 4.0e-4 covers all with margin).
__global__ __launch_bounds__(256)
void k_combine3(const int* __restrict__ pk1, const int* __restrict__ pk2,
                const float* __restrict__ l1b,
                float* __restrict__ out_idx, float* __restrict__ counts,
                int* __restrict__ flaglist, int* __restrict__ flagn) {
    int n = blockIdx.x * 256 + threadIdx.x;
    int m1 = 0x7FFFFFFF, m2 = 0x7FFFFFFF;
#pragma unroll
    for (int c = 0; c < 4; ++c) {
        int a1 = pk1[c * N_TOT + n];
        int a2 = pk2[c * N_TOT + n];
        int mx = imax(m1, a1);
        m1 = imin(m1, a1);
        m2 = imin(imin(m2, a2), mx);
    }
    int i1 = m1 & 1023;
    out_idx[n] = (float)i1;
    atomicAdd(counts + i1, 1.0f);
    int t1 = m1 >> 10, t2 = m2 >> 10;   // arithmetic shift = floor, exact
    float thr = l1b[n] * 2.9e-6f + 4.0e-4f;
    int thrq = (int)(thr * 0x1p21f);
    if (t2 - t1 <= thrq) {
        int p = atomicAdd(flagn, 1);
        flaglist[p] = n;
    }
}

// ---------------------------------------------------------------------------
// Transpose z_e [64][256][1024] -> zflat [65536][256] (into O_ZQ region,
// overwriting the dead fp16/partial scratch; runs BEFORE the rescue so the
// rescue gets coalesced row reads).
__global__ __launch_bounds__(256)
void k_zt(const float* __restrict__ ze, float* __restrict__ zflat) {
    __shared__ float tile[64][65];
    const int t = threadIdx.x;
    const int hw0 = blockIdx.x * 64;
    const int d0  = blockIdx.y * 64;
    const int b   = blockIdx.z;
    const size_t base_in = (size_t)b * (D_DIM * HW_SZ);
#pragma unroll
    for (int p = 0; p < 4; ++p) {
        int dd = p * 16 + (t >> 4);
        int c4 = (t & 15) * 4;
        float4 v = *(const float4*)(ze + base_in + (size_t)(d0 + dd) * HW_SZ + hw0 + c4);
        tile[dd][c4 + 0] = v.x;
        tile[dd][c4 + 1] = v.y;
        tile[dd][c4 + 2] = v.z;
        tile[dd][c4 + 3] = v.w;
    }
    __syncthreads();
#pragma unroll
    for (int p = 0; p < 4; ++p) {
        int hh  = p * 16 + (t >> 4);
        int dc4 = (t & 15) * 4;
        float4 v = { tile[dc4 + 0][hh], tile[dc4 + 1][hh],
                     tile[dc4 + 2][hh], tile[dc4 + 3][hh] };
        *(float4*)(zflat + (size_t)(b * HW_SZ + hw0 + hh) * D_DIM + d0 + dc4) = v;
    }
}

// ---------------------------------------------------------------------------
// Exact rescue v3 (unchanged): register-GEMM over flagged rows only.
// Arithmetic identical to the original exact path: sequential pk-fma over
// ascending d; s = fl(zn - 2G) + cn; lexicographic (value, index) min.
__global__ __launch_bounds__(256)
void k_rescue3(const float* __restrict__ zflat, const float* __restrict__ ct,
               const float* __restrict__ cn, const float* __restrict__ znb,
               const int* __restrict__ flaglist, const int* __restrict__ flagn,
               float* __restrict__ out_idx, float* __restrict__ counts) {
    __shared__ float zl[8][256];     // [row][d]; broadcast reads
    __shared__ float znl[8];
    __shared__ float cnl[1024];
    __shared__ float redv[4][8];
    __shared__ int   redi[4][8];
    __shared__ int   rows[8];
    const int t  = threadIdx.x;
    const int w  = t >> 6;           // wave: codes w*256 .. w*256+255
    const int tx = t & 63;           // lane: codes w*256 + tx*4 .. +3
    const int nf = *flagn;
#pragma unroll
    for (int i = 0; i < 4; ++i) cnl[i * 256 + t] = cn[i * 256 + t];

    const float* cbase = ct + w * 256 + tx * 4;
    const int kbase = w * 256 + tx * 4;

#define LD(i) (*(const float4*)(cbase + (size_t)(i) * K_CODES))

    for (int grp = blockIdx.x; grp * 8 < nf; grp += 1024) {
        __syncthreads();             // prev group fully done (zl/rows reuse)
        if (t < 8) {
            int ii = grp * 8 + t;
            int n = flaglist[ii < nf ? ii : nf - 1];
            rows[t] = n;
            znl[t] = znb[n];
        }
        __syncthreads();
        // stage 8 z rows, coalesced from zflat
#pragma unroll
        for (int r = 0; r < 8; ++r)
            zl[r][t] = zflat[(size_t)rows[r] * D_DIM + t];
        __syncthreads();

        f2 acc2[8][2];
#pragma unroll
        for (int r = 0; r < 8; ++r) { acc2[r][0] = (f2)0.f; acc2[r][1] = (f2)0.f; }

        float4 p0 = LD(0), p1 = LD(1), p2 = LD(2), p3 = LD(3);
        for (int d = 0; d < 256; d += 4) {
            float4 zr[8];
#pragma unroll
            for (int r = 0; r < 8; ++r)
                zr[r] = *(const float4*)&zl[r][d];
            // d+0
#pragma unroll
            for (int r = 0; r < 8; ++r) {
                f2 zj = { zr[r].x, zr[r].x };
                acc2[r][0] = __builtin_elementwise_fma(zj, (f2){p0.x, p0.y}, acc2[r][0]);
                acc2[r][1] = __builtin_elementwise_fma(zj, (f2){p0.z, p0.w}, acc2[r][1]);
            }
            p0 = LD(d + 4);          // reads <= row 259: 3 rows past CT, in-bounds of d_out
            // d+1
#pragma unroll
            for (int r = 0; r < 8; ++r) {
                f2 zj = { zr[r].y, zr[r].y };
                acc2[r][0] = __builtin_elementwise_fma(zj, (f2){p1.x, p1.y}, acc2[r][0]);
                acc2[r][1] = __builtin_elementwise_fma(zj, (f2){p1.z, p1.w}, acc2[r][1]);
            }
            p1 = LD(d + 5);
            // d+2
#pragma unroll
            for (int r = 0; r < 8; ++r) {
                f2 zj = { zr[r].z, zr[r].z };
                acc2[r][0] = __builtin_elementwise_fma(zj, (f2){p2.x, p2.y}, acc2[r][0]);
                acc2[r][1] = __builtin_elementwise_fma(zj, (f2){p2.z, p2.w}, acc2[r][1]);
            }
            p2 = LD(d + 6);
            // d+3
#pragma unroll
            for (int r = 0; r < 8; ++r) {
                f2 zj = { zr[r].w, zr[r].w };
                acc2[r][0] = __builtin_elementwise_fma(zj, (f2){p3.x, p3.y}, acc2[r][0]);
                acc2[r][1] = __builtin_elementwise_fma(zj, (f2){p3.z, p3.w}, acc2[r][1]);
            }
            p3 = LD(d + 7);
        }

        // fold + reduce, one row at a time
#pragma unroll
        for (int r = 0; r < 8; ++r) {
            float znv = znl[r];
            float bs = INFINITY; int bk = 0;
            float a0 = acc2[r][0].x, a1 = acc2[r][0].y;
            float a2 = acc2[r][1].x, a3 = acc2[r][1].y;
            {
                float s0 = (znv - 2.0f * a0) + cnl[kbase + 0];
                float s1 = (znv - 2.0f * a1) + cnl[kbase + 1];
                float s2 = (znv - 2.0f * a2) + cnl[kbase + 2];
                float s3 = (znv - 2.0f * a3) + cnl[kbase + 3];
                bs = s0; bk = kbase;
                if (s1 < bs) { bs = s1; bk = kbase + 1; }
                if (s2 < bs) { bs = s2; bk = kbase + 2; }
                if (s3 < bs) { bs = s3; bk = kbase + 3; }
            }
            for (int off = 1; off < 64; off <<= 1) {
                float os = __shfl_xor(bs, off, 64);
                int   ok = __shfl_xor(bk, off, 64);
                if (os < bs || (os == bs && ok < bk)) { bs = os; bk = ok; }
            }
            if (tx == 0) { redv[w][r] = bs; redi[w][r] = bk; }
        }
        __syncthreads();
        if (t < 8 && grp * 8 + t < nf) {
            float bs = redv[0][t]; int bk = redi[0][t];
#pragma unroll
            for (int w2 = 1; w2 < 4; ++w2) {
                float os = redv[w2][t];   // ascending wave = ascending k
                int   ok = redi[w2][t];
                if (os < bs) { bs = os; bk = ok; }
            }
            int n = rows[t];
            int old = (int)out_idx[n];
            if (old != bk) {
                out_idx[n] = (float)bk;
                atomicAdd(counts + old, -1.0f);
                atomicAdd(counts + bk,  1.0f);
            }
        }
    }
#undef LD
}

// ---------------------------------------------------------------------------
// EMA cluster size + smoothed (loss finalize lives in k_zq).
__global__ __launch_bounds__(1024)
void k_ema_cs(const float* __restrict__ ema_cs, const float* __restrict__ counts,
              float* __restrict__ out_cs, float* __restrict__ smoothed) {
    __shared__ float red[1024];
    int k = threadIdx.x;
    float cs_new = fmaf(0.99f, ema_cs[k], 0.01f * counts[k]);
    red[k] = cs_new;
    __syncthreads();
    for (int off = 512; off > 0; off >>= 1) {
        if (k < off) red[k] += red[k + off];
        __syncthreads();
    }
    float ntot = red[0];
    out_cs[k] = cs_new;
    smoothed[k] = (cs_new + 1e-5f) / (ntot + 0.01024f) * ntot;
}

// ---------------------------------------------------------------------------
// Per-code segment sum: one block per code; compact matching rows into an LDS
// queue (float4 index scan), sum rows coalesced from zflat with 2-way load
// ILP. Fuses loss partials + dw EMA + cb write.
__global__ __launch_bounds__(256)
void k_dwsum(const float* __restrict__ idxf, const float* __restrict__ zflat,
             const float* __restrict__ cb, const float* __restrict__ ema_dw,
             const float* __restrict__ smoothed, float* __restrict__ out_dw,
             float* __restrict__ out_cb, float* __restrict__ lossacc) {
    __shared__ int queue[4096];
    __shared__ int qn;
    __shared__ float lred[4];

    const int k = blockIdx.x;
    const int t = threadIdx.x;
    const float fk = (float)k;
    const float ck = cb[(size_t)k * D_DIM + t];

    float acc = 0.f;
    float ls  = 0.f;

    for (int chunk = 0; chunk < 16; ++chunk) {
        if (t == 0) qn = 0;
        __syncthreads();
#pragma unroll
        for (int j = 0; j < 4; ++j) {
            int nb = chunk * 4096 + j * 1024 + t * 4;   // coalesced float4 scan
            float4 iv = *(const float4*)(idxf + nb);
            if (iv.x == fk) { int p = atomicAdd(&qn, 1); queue[p] = nb; }
            if (iv.y == fk) { int p = atomicAdd(&qn, 1); queue[p] = nb + 1; }
            if (iv.z == fk) { int p = atomicAdd(&qn, 1); queue[p] = nb + 2; }
            if (iv.w == fk) { int p = atomicAdd(&qn, 1); queue[p] = nb + 3; }
        }
        __syncthreads();
        int m = qn;
        int i = 0;
        for (; i + 1 < m; i += 2) {                    // 2-way load ILP
            int n1 = queue[i], n2 = queue[i + 1];
            float z1 = zflat[(size_t)n1 * D_DIM + t];
            float z2 = zflat[(size_t)n2 * D_DIM + t];
            acc += z1; float d1 = ck - z1; ls += d1 * d1;
            acc += z2; float d2 = ck - z2; ls += d2 * d2;
        }
        if (i < m) {
            int n1 = queue[i];
            float z1 = zflat[(size_t)n1 * D_DIM + t];
            acc += z1; float d1 = ck - z1; ls += d1 * d1;
        }
        __syncthreads();   // all queue reads done before next chunk's writes
    }

    size_t o = (size_t)k * D_DIM + t;
    float nd = fmaf(0.99f, ema_dw[o], 0.01f * acc);
    out_dw[o] = nd;
    out_cb[o] = nd / smoothed[k];

#pragma unroll
    for (int off = 32; off > 0; off >>= 1) ls += __shfl_down(ls, off, 64);
    if ((t & 63) == 0) lred[t >> 6] = ls;
    __syncthreads();
    if (t == 0) atomicAdd(lossacc, lred[0] + lred[1] + lred[2] + lred[3]);
}

// ---------------------------------------------------------------------------
// Straight-through z_q writer: pure float4 stream + L2 codebook gather.
// Grid 1024 blocks (4x the old 256): each block covers a 16-d slice.
// Also finalizes the loss (lossacc complete from k_dwsum, stream-ordered).
__global__ __launch_bounds__(256)
void k_zq(const float* __restrict__ ze, const float* __restrict__ cb,
          const float* __restrict__ idxf, float* __restrict__ out0,
          const float* __restrict__ lossacc, float* __restrict__ out_loss) {
    const int t = threadIdx.x;
    int q   = blockIdx.x & 3;                  // d-16 segment
    int g   = (blockIdx.x >> 2) * 64 + (t & 63);   // hw4-group id in [0, 16384)
    int b   = g >> 8;
    int hwl = (g & 255) * 4;
    int dg  = t >> 6;                          // d-quarter (0..3)
    const size_t base = (size_t)b * (D_DIM * HW_SZ) + hwl;

    int i0 = (int)idxf[b * HW_SZ + hwl + 0];
    int i1 = (int)idxf[b * HW_SZ + hwl + 1];
    int i2 = (int)idxf[b * HW_SZ + hwl + 2];
    int i3 = (int)idxf[b * HW_SZ + hwl + 3];
    const float* c0 = cb + (size_t)i0 * D_DIM;
    const float* c1 = cb + (size_t)i1 * D_DIM;
    const float* c2 = cb + (size_t)i2 * D_DIM;
    const float* c3 = cb + (size_t)i3 * D_DIM;

#pragma unroll 4
    for (int i = 0; i < 16; ++i) {
        int d = dg * 64 + q * 16 + i;
        size_t o = base + (size_t)d * HW_SZ;
        float4 z = *(const float4*)(ze + o);
        float4 r;
        r.x = z.x + (c0[d] - z.x);
        r.y = z.y + (c1[d] - z.y);
        r.z = z.z + (c2[d] - z.z);
        r.w = z.w + (c3[d] - z.w);
        *(float4*)(out0 + o) = r;
    }

    if (blockIdx.x == 0 && t == 0)
        out_loss[0] = 0.5f * lossacc[0] / ND_TOT;
}

// ---------------------------------------------------------------------------
extern "C" void kernel_launch(void* const* d_in, const int* in_sizes, int n_in,
                              void* d_out, int out_size, void* d_ws, size_t ws_size,
                              hipStream_t stream) {
    const float* ze     = (const float*)d_in[0];  // [64,256,32,32]
    const float* cb     = (const float*)d_in[1];  // [1024,256]
    const float* emacs  = (const float*)d_in[2];  // [1024]
    const float* emadw  = (const float*)d_in[3];  // [1024,256]
    float* out = (float*)d_out;
    float* ws  = (float*)d_ws;

    // Scratch choreography (stream-ordered reuse of d_out):
    //   O_ZQ region: ZH/CH (prep -> margmin), PK1/PK2 (margmin -> combine3),
    //     L1 (zn2 -> combine3) — all dead before k_zt writes zflat there;
    //     zflat (zt -> rescue3/dwsum) — overwritten by k_zq at the end.
    //   Tail: CT at O_CB (transpose -> rescue3, then out_cb by dwsum);
    //     ZN + FLAG at O_DW (zn2/combine3 -> rescue3, then out_dw by dwsum).
    f16*   ZH    = (f16*)(out + ZHALF_OFF);
    f16*   CH    = (f16*)(out + CHALF_OFF);
    int*   PK2   = (int*)(out + PK2_OFF);
    int*   PK1   = (int*)(out + PK1_OFF);
    float* L1b   = out + L1_OFF;
    float* ZFLAT = out;
    float* CT    = out + O_CB;
    float* ZNb   = out + O_DW;
    int*   FLAG  = (int*)(out + O_DW + 65536);
    // d_ws scratch
    float* counts   = ws;                 // 1024
    float* lossacc  = ws + 1024;          // 1
    int*   flagn    = (int*)(ws + 1025);  // 1
    float* smoothed = ws + 1088;          // 1024
    float* CN       = ws + 2112;          // 1024

    hipMemsetAsync(ws, 0, 1032 * sizeof(float), stream);

    k_transpose<<<dim3(32, 8), 256, 0, stream>>>(cb, CT);
    k_cnorm<<<4, 256, 0, stream>>>(cb, CN);
    k_zn2<<<256, 256, 0, stream>>>(ze, ZNb, L1b);
    k_prep_c<<<256, 256, 0, stream>>>(cb, CH);
    k_prep_z<<<dim3(16, 4, 64), 256, 0, stream>>>(ze, ZH);
    k_margmin<<<dim3(512, 4), 256, 0, stream>>>(ZH, CH, CN, PK1, PK2);
    k_combine3<<<256, 256, 0, stream>>>(PK1, PK2, L1b, out + O_IDX, counts,
                                        FLAG, flagn);
    k_zt<<<dim3(16, 4, 64), 256, 0, stream>>>(ze, ZFLAT);
    k_rescue3<<<1024, 256, 0, stream>>>(ZFLAT, CT, CN, ZNb, FLAG, flagn,
                                        out + O_IDX, counts);
    k_ema_cs<<<1, 1024, 0, stream>>>(emacs, counts, out + O_CS, smoothed);
    k_dwsum<<<K_CODES, 256, 0, stream>>>(out + O_IDX, ZFLAT, cb, emadw, smoothed,
                                         out + O_DW, out + O_CB, lossacc);
    k_zq<<<1024, 256, 0, stream>>>(ze, cb, out + O_IDX, out + O_ZQ,
                                   lossacc, out + O_LOSS);
}